// Round 6
// baseline (1452.734 us; speedup 1.0000x reference)
//
#include <hip/hip_runtime.h>
#include <hip/hip_bf16.h>

// B=4, S=2048, D_MODEL=1024, H=16, E=64, M=8192 rows, bh = b*16+h (64)
// Precision: fp32 value = hi + lo (2x fp16, ~24 mantissa bits, fp32-exact).
// Products via 3 MFMA passes (hh, hl, lh); ll ~ 2^-24 rel -> dropped.
// V path and PV/O GEMMs: single-pass fp16 (error << thresholds).
// MFMA shape: mfma_f32_16x16x32_f16.
//   A-frag: lane l holds A[m=l&15][k=(l>>4)*8+j]  (16B contiguous)
//   B-frag: lane l holds B[k=(l>>4)*8+j][n=l&15]  (read from [n][k]-major array)
//   C/D  : lane l holds D[row=(l>>4)*4+r][col=l&15]

typedef _Float16 half_t;
typedef __attribute__((ext_vector_type(8))) _Float16 f16x8;
typedef __attribute__((ext_vector_type(4))) _Float16 f16x4;
typedef __attribute__((ext_vector_type(4))) float f32x4;

#define MFMA16(a, b, c) __builtin_amdgcn_mfma_f32_16x16x32_f16(a, b, c, 0, 0, 0)

__device__ __forceinline__ void split2(float v, half_t& h, half_t& l) {
    h = (half_t)v;
    l = (half_t)(v - (float)h);
}

// ---------------------------------------------------------------------------
// x [8192][1024] fp32 -> xh, xl fp16 planes
// ---------------------------------------------------------------------------
__global__ __launch_bounds__(256) void k_conv_x(
    const float* __restrict__ x, half_t* __restrict__ xh, half_t* __restrict__ xl)
{
    const size_t i = ((size_t)blockIdx.x * 256 + threadIdx.x) * 8;
    float4 a = *(const float4*)&x[i];
    float4 b = *(const float4*)&x[i + 4];
    float v[8] = {a.x, a.y, a.z, a.w, b.x, b.y, b.z, b.w};
    f16x8 H, L;
    #pragma unroll
    for (int j = 0; j < 8; ++j) {
        half_t hh, hl; split2(v[j], hh, hl);
        H[j] = hh; L[j] = hl;
    }
    *(f16x8*)&xh[i] = H;
    *(f16x8*)&xl[i] = L;
}

// ---------------------------------------------------------------------------
// W_{Q,K,V} [16][1024 d][64 e] fp32 -> wh, wl fp16 [n=3072][k=1024] (transposed)
// ---------------------------------------------------------------------------
__global__ __launch_bounds__(256) void k_conv_w(
    const float* __restrict__ Wq, const float* __restrict__ Wk, const float* __restrict__ Wv,
    half_t* __restrict__ wh, half_t* __restrict__ wl)
{
    const int bid = blockIdx.x;
    const int mat = bid >> 8, h = (bid >> 4) & 15, dt = bid & 15;
    const float* W = (mat == 0) ? Wq : (mat == 1) ? Wk : Wv;
    __shared__ float t[64][65];
    const int tid = threadIdx.x;
    #pragma unroll
    for (int rep = 0; rep < 4; ++rep) {
        int idx = tid + rep * 256;
        int r = idx >> 4, c4 = (idx & 15) * 4;
        float4 v4 = *(const float4*)&W[(size_t)h * 65536 + (size_t)(dt * 64 + r) * 64 + c4];
        t[r][c4 + 0] = v4.x; t[r][c4 + 1] = v4.y;
        t[r][c4 + 2] = v4.z; t[r][c4 + 3] = v4.w;
    }
    __syncthreads();
    #pragma unroll
    for (int rep = 0; rep < 4; ++rep) {
        int idx = tid + rep * 256;
        int e = idx >> 4, g = (idx & 15) * 4;
        size_t o = ((size_t)(mat * 1024 + h * 64 + e)) * 1024 + dt * 64 + g;
        #pragma unroll
        for (int j = 0; j < 4; ++j) {
            half_t hh, hl; split2(t[g + j][e], hh, hl);
            wh[o + j] = hh; wl[o + j] = hl;
        }
    }
}

// W_O [1024 hd][1024 dm] fp32 -> woT fp16 [dm][hd]
__global__ __launch_bounds__(256) void k_conv_wo(
    const float* __restrict__ Wo, half_t* __restrict__ woT)
{
    const int bi = blockIdx.x >> 4, bj = blockIdx.x & 15;
    __shared__ float t[64][65];
    const int tid = threadIdx.x;
    #pragma unroll
    for (int rep = 0; rep < 4; ++rep) {
        int idx = tid + rep * 256;
        int r = idx >> 4, c4 = (idx & 15) * 4;
        float4 v4 = *(const float4*)&Wo[(size_t)(bi * 64 + r) * 1024 + bj * 64 + c4];
        t[r][c4 + 0] = v4.x; t[r][c4 + 1] = v4.y;
        t[r][c4 + 2] = v4.z; t[r][c4 + 3] = v4.w;
    }
    __syncthreads();
    #pragma unroll
    for (int rep = 0; rep < 4; ++rep) {
        int idx = tid + rep * 256;
        int dm = idx >> 4, g = (idx & 15) * 4;
        size_t o = (size_t)(bj * 64 + dm) * 1024 + bi * 64 + g;
        #pragma unroll
        for (int j = 0; j < 4; ++j)
            woT[o + j] = (half_t)t[g + j][dm];
    }
}

// ---------------------------------------------------------------------------
// QKV projection GEMM: M=8192, N=3072, K=1024.
// Q/K n-blocks: 3-pass fp16-split; V n-blocks (n0>=2048): 1-pass.
// ---------------------------------------------------------------------------
__global__ __launch_bounds__(256) void k_proj(
    const half_t* __restrict__ xh, const half_t* __restrict__ xl,
    const half_t* __restrict__ wh, const half_t* __restrict__ wl,
    const float* __restrict__ bq, const float* __restrict__ bk, const float* __restrict__ bv,
    half_t* __restrict__ oqh, half_t* __restrict__ oql,
    half_t* __restrict__ okh, half_t* __restrict__ okl,
    half_t* __restrict__ ovT)
{
    __shared__ half_t lds[2][4][128 * 32];
    const int tid = threadIdx.x, w = tid >> 6, lane = tid & 63;
    const int l15 = lane & 15, lhi = lane >> 4;
    const int wm = w >> 1, wn = w & 1;
    const int m0 = blockIdx.y * 128, n0 = blockIdx.x * 128;
    const bool isv = (n0 >= 2048);          // V block: single-pass

    const int r0 = w * 32 + (lane >> 2);
    const int r1 = r0 + 16;
    const int u  = lane & 3;
    const size_t gA0 = (size_t)(m0 + r0) * 1024 + u * 8;
    const size_t gA1 = (size_t)(m0 + r1) * 1024 + u * 8;
    const size_t gB0 = (size_t)(n0 + r0) * 1024 + u * 8;
    const size_t gB1 = (size_t)(n0 + r1) * 1024 + u * 8;
    const int d0 = r0 * 32 + ((u ^ ((r0 >> 1) & 3)) * 8);
    const int d1 = r1 * 32 + ((u ^ ((r1 >> 1) & 3)) * 8);

    int4 st[8];
    auto LOAD = [&](int kb) {
        st[0] = *(const int4*)&xh[gA0 + kb];
        st[1] = *(const int4*)&xh[gA1 + kb];
        st[4] = *(const int4*)&wh[gB0 + kb];
        st[5] = *(const int4*)&wh[gB1 + kb];
        if (!isv) {
            st[2] = *(const int4*)&xl[gA0 + kb];
            st[3] = *(const int4*)&xl[gA1 + kb];
            st[6] = *(const int4*)&wl[gB0 + kb];
            st[7] = *(const int4*)&wl[gB1 + kb];
        }
    };
    auto WRITE = [&](int bf) {
        *(int4*)&lds[bf][0][d0] = st[0];
        *(int4*)&lds[bf][0][d1] = st[1];
        *(int4*)&lds[bf][2][d0] = st[4];
        *(int4*)&lds[bf][2][d1] = st[5];
        if (!isv) {
            *(int4*)&lds[bf][1][d0] = st[2];
            *(int4*)&lds[bf][1][d1] = st[3];
            *(int4*)&lds[bf][3][d0] = st[6];
            *(int4*)&lds[bf][3][d1] = st[7];
        }
    };

    f32x4 acc[4][4] = {};

    LOAD(0); WRITE(0); __syncthreads();
    int cur = 0;
    for (int ks = 0; ks < 32; ++ks) {
        if (ks < 31) LOAD((ks + 1) * 32);
        f16x8 fah[4], fal[4], fbh[4], fbl[4];
        #pragma unroll
        for (int i = 0; i < 4; ++i) {
            const int ra = wm * 64 + i * 16 + l15;
            const int aa = ra * 32 + ((lhi ^ ((ra >> 1) & 3)) * 8);
            fah[i] = *(const f16x8*)&lds[cur][0][aa];
            const int rb = wn * 64 + i * 16 + l15;
            const int ab = rb * 32 + ((lhi ^ ((rb >> 1) & 3)) * 8);
            fbh[i] = *(const f16x8*)&lds[cur][2][ab];
            if (!isv) {
                fal[i] = *(const f16x8*)&lds[cur][1][aa];
                fbl[i] = *(const f16x8*)&lds[cur][3][ab];
            }
        }
        if (isv) {
            #pragma unroll
            for (int mi = 0; mi < 4; ++mi)
                #pragma unroll
                for (int ni = 0; ni < 4; ++ni)
                    acc[mi][ni] = MFMA16(fah[mi], fbh[ni], acc[mi][ni]);
        } else {
            #pragma unroll
            for (int mi = 0; mi < 4; ++mi)
                #pragma unroll
                for (int ni = 0; ni < 4; ++ni) {
                    acc[mi][ni] = MFMA16(fah[mi], fbh[ni], acc[mi][ni]);
                    acc[mi][ni] = MFMA16(fah[mi], fbl[ni], acc[mi][ni]);
                    acc[mi][ni] = MFMA16(fal[mi], fbh[ni], acc[mi][ni]);
                }
        }
        if (ks < 31) WRITE(cur ^ 1);
        __syncthreads();
        cur ^= 1;
    }

    #pragma unroll
    for (int ni = 0; ni < 4; ++ni) {
        const int n = n0 + wn * 64 + ni * 16 + l15;
        const int mat = n >> 10, nn = n & 1023;
        const int h = nn >> 6, e = nn & 63;
        const float bias = (mat == 0 ? bq : mat == 1 ? bk : bv)[h * 64 + e];
        #pragma unroll
        for (int mi = 0; mi < 4; ++mi)
            #pragma unroll
            for (int r = 0; r < 4; ++r) {
                const int m = m0 + wm * 64 + mi * 16 + lhi * 4 + r;
                const int b = m >> 11, s = m & 2047;
                const int bh_i = b * 16 + h;
                const float v = acc[mi][ni][r] + bias;
                if (mat == 2) {
                    ovT[((size_t)bh_i * 64 + e) * 2048 + s] = (half_t)v;
                } else {
                    half_t hh, hl; split2(v, hh, hl);
                    const size_t o = ((size_t)bh_i * 2048 + s) * 64 + e;
                    if (mat == 0) { oqh[o] = hh; oql[o] = hl; }
                    else          { okh[o] = hh; okl[o] = hl; }
                }
            }
    }
}

// ---------------------------------------------------------------------------
// Fused attention, recompute flavor. Per (qt, bh) block of 64 q-rows.
// Phase A: QK^T 3-pass MFMA per k-tile, online (m,l) in registers only.
//          After the 16-lane shuffle reduce, each thread's m[4]/l[4] are the
//          final stats for exactly the rows its C-fragments own.
// Phase B: recompute QK^T, p = exp(s-m)*inv (final value), bounce fp16 p
//          through swizzled LDS -> coalesced fp32 pattern write + PV A-frags;
//          z = P*V via fp16 MFMA.  Zero-fill above diagonal.
// LDS: 2x2x8KB K staging + 8KB pa = 40 KB -> 4 blocks/CU.
// ---------------------------------------------------------------------------
__global__ __launch_bounds__(256) void k_attn(
    const half_t* __restrict__ qh, const half_t* __restrict__ ql,
    const half_t* __restrict__ kh, const half_t* __restrict__ kl,
    const half_t* __restrict__ vT,
    float* __restrict__ pattern, half_t* __restrict__ z)
{
    __shared__ half_t kst[2][2][64 * 64];   // [buf][hi/lo][swizzled] 32 KB
    __shared__ half_t pa[64 * 64];          // swizzled p tile, 8 KB

    const int qt = 31 - blockIdx.x, bh = blockIdx.y;
    const int b = bh >> 4, h = bh & 15;
    const int tid = threadIdx.x, w = tid >> 6, lane = tid & 63;
    const int l15 = lane & 15, lhi = lane >> 4;
    const int q0 = qt * 64, rw = q0 + w * 16;

    // Q fragments (persist both phases)
    const size_t qrow = ((size_t)bh * 2048 + rw + l15) * 64;
    f16x8 aqh[2], aql[2];
    #pragma unroll
    for (int ch = 0; ch < 2; ++ch) {
        aqh[ch] = *(const f16x8*)&qh[qrow + ch * 32 + lhi * 8];
        aql[ch] = *(const f16x8*)&ql[qrow + ch * 32 + lhi * 8];
    }

    // K staging (swizzled): wave w covers key-rows w*16..+16
    const int sr0 = w * 16 + (lane >> 3);
    const int sr1 = sr0 + 8;
    const int su  = lane & 7;
    const size_t kbase = (size_t)bh * 2048 * 64;
    const int sd0 = sr0 * 64 + ((su ^ (sr0 & 7)) * 8);
    const int sd1 = sr1 * 64 + ((su ^ (sr1 & 7)) * 8);

    int4 st[4];
    auto LOADK = [&](int kt) {
        const size_t g0 = kbase + (size_t)(kt * 64 + sr0) * 64 + su * 8;
        const size_t g1 = kbase + (size_t)(kt * 64 + sr1) * 64 + su * 8;
        st[0] = *(const int4*)&kh[g0];
        st[1] = *(const int4*)&kh[g1];
        st[2] = *(const int4*)&kl[g0];
        st[3] = *(const int4*)&kl[g1];
    };
    auto WRITEK = [&](int bf) {
        *(int4*)&kst[bf][0][sd0] = st[0];
        *(int4*)&kst[bf][0][sd1] = st[1];
        *(int4*)&kst[bf][1][sd0] = st[2];
        *(int4*)&kst[bf][1][sd1] = st[3];
    };
    // QK^T for one staged tile -> acc (scaled + masked)
    auto QKTILE = [&](int cur, int kt, f32x4* acc) {
        #pragma unroll
        for (int nt = 0; nt < 4; ++nt) {
            const int kr = nt * 16 + l15;
            #pragma unroll
            for (int ch = 0; ch < 2; ++ch) {
                const int slot = ch * 4 + lhi;
                const int ad = kr * 64 + ((slot ^ (kr & 7)) * 8);
                f16x8 bh8 = *(const f16x8*)&kst[cur][0][ad];
                f16x8 bl8 = *(const f16x8*)&kst[cur][1][ad];
                acc[nt] = MFMA16(aqh[ch], bh8, acc[nt]);
                acc[nt] = MFMA16(aqh[ch], bl8, acc[nt]);
                acc[nt] = MFMA16(aql[ch], bh8, acc[nt]);
            }
        }
        const bool diag = (kt == qt);
        #pragma unroll
        for (int nt = 0; nt < 4; ++nt) {
            const int key = kt * 64 + nt * 16 + l15;
            #pragma unroll
            for (int r = 0; r < 4; ++r) {
                float s = acc[nt][r] * 0.125f;
                const int row = rw + lhi * 4 + r;
                if (diag && key > row) s = -1e30f;
                acc[nt][r] = s;
            }
        }
    };

    float m[4], l[4];
    #pragma unroll
    for (int r = 0; r < 4; ++r) { m[r] = -1e30f; l[r] = 0.f; }

    // ---- Phase A: stats only ----
    LOADK(0); WRITEK(0); __syncthreads();
    int cur = 0;
    for (int kt = 0; kt <= qt; ++kt) {
        if (kt < qt) LOADK(kt + 1);
        f32x4 acc[4] = {};
        QKTILE(cur, kt, acc);
        float tmax[4] = {-1e30f, -1e30f, -1e30f, -1e30f};
        #pragma unroll
        for (int nt = 0; nt < 4; ++nt)
            #pragma unroll
            for (int r = 0; r < 4; ++r)
                tmax[r] = fmaxf(tmax[r], acc[nt][r]);
        #pragma unroll
        for (int off = 1; off < 16; off <<= 1)
            #pragma unroll
            for (int r = 0; r < 4; ++r)
                tmax[r] = fmaxf(tmax[r], __shfl_xor(tmax[r], off));
        float esum[4] = {0.f, 0.f, 0.f, 0.f};
        #pragma unroll
        for (int nt = 0; nt < 4; ++nt)
            #pragma unroll
            for (int r = 0; r < 4; ++r)
                esum[r] += __expf(acc[nt][r] - tmax[r]);
        #pragma unroll
        for (int off = 1; off < 16; off <<= 1)
            #pragma unroll
            for (int r = 0; r < 4; ++r)
                esum[r] += __shfl_xor(esum[r], off);
        #pragma unroll
        for (int r = 0; r < 4; ++r) {
            const float mn = fmaxf(m[r], tmax[r]);
            l[r] = l[r] * __expf(m[r] - mn) + esum[r] * __expf(tmax[r] - mn);
            m[r] = mn;
        }
        if (kt < qt) WRITEK(cur ^ 1);
        __syncthreads();
        cur ^= 1;
    }

    float inv[4];
    #pragma unroll
    for (int r = 0; r < 4; ++r) inv[r] = 1.f / l[r];

    // ---- Phase B: recompute + emit ----
    const int r_    = tid >> 4;            // streaming row within 16-group
    const int c0    = (tid & 15) * 4;      // streaming col (floats)
    const int chunk = c0 >> 3;
    const int cin   = c0 & 7;
    const int arow  = w * 16 + l15;        // A-frag row
    const size_t prow_base = ((size_t)bh * 2048 + q0) * 2048;

    f32x4 acc2[4] = {};
    LOADK(0); WRITEK(0); __syncthreads();
    cur = 0;
    for (int kt = 0; kt < 32; ++kt) {
        if (kt <= qt) {
            if (kt < qt) LOADK(kt + 1);
            f32x4 acc[4] = {};
            QKTILE(cur, kt, acc);
            // p = exp(s - m) * inv -> swizzled fp16 pa
            #pragma unroll
            for (int nt = 0; nt < 4; ++nt) {
                const int col = nt * 16 + l15;
                const int cc = col >> 3, ci = col & 7;
                #pragma unroll
                for (int r = 0; r < 4; ++r) {
                    const int row = w * 16 + lhi * 4 + r;
                    const float p = __expf(acc[nt][r] - m[r]) * inv[r];
                    pa[row * 64 + ((cc ^ (row & 7)) * 8) + ci] = (half_t)p;
                }
            }
            __syncthreads();   // pa ready
            // PV MFMA from pa A-frags + global V B-frags
            #pragma unroll
            for (int ch = 0; ch < 2; ++ch) {
                const int slot = ch * 4 + lhi;
                f16x8 af = *(const f16x8*)&pa[arow * 64 + ((slot ^ (arow & 7)) * 8)];
                #pragma unroll
                for (int nt = 0; nt < 4; ++nt) {
                    f16x8 bf8 = *(const f16x8*)&vT[((size_t)bh * 64 + nt * 16 + l15) * 2048
                                                   + kt * 64 + ch * 32 + lhi * 8];
                    acc2[nt] = MFMA16(af, bf8, acc2[nt]);
                }
            }
            // coalesced fp32 pattern write from pa
            #pragma unroll
            for (int rep = 0; rep < 4; ++rep) {
                const int row = rep * 16 + r_;
                f16x4 pv4 = *(const f16x4*)&pa[row * 64 + ((chunk ^ (row & 7)) * 8) + cin];
                float4 p;
                p.x = (float)pv4[0]; p.y = (float)pv4[1];
                p.z = (float)pv4[2]; p.w = (float)pv4[3];
                *(float4*)&pattern[prow_base + (size_t)row * 2048 + kt * 64 + c0] = p;
            }
            if (kt < qt) WRITEK(cur ^ 1);
            __syncthreads();   // kst[cur^1] ready; pa reads done
            cur ^= 1;
        } else {
            float4 zz; zz.x = 0.f; zz.y = 0.f; zz.z = 0.f; zz.w = 0.f;
            #pragma unroll
            for (int rep = 0; rep < 4; ++rep) {
                const int row = rep * 16 + r_;
                *(float4*)&pattern[prow_base + (size_t)row * 2048 + kt * 64 + c0] = zz;
            }
        }
    }

    #pragma unroll
    for (int nt = 0; nt < 4; ++nt) {
        const int e = nt * 16 + l15;
        #pragma unroll
        for (int r = 0; r < 4; ++r) {
            const int row = rw + lhi * 4 + r;
            z[((size_t)(b * 2048 + row)) * 1024 + h * 64 + e] = (half_t)acc2[nt][r];
        }
    }
}

// ---------------------------------------------------------------------------
// O projection GEMM: M=8192, N=1024, K=1024, 1-pass fp16 MFMA.
// ---------------------------------------------------------------------------
__global__ __launch_bounds__(256) void k_oproj(
    const half_t* __restrict__ z, const half_t* __restrict__ woT,
    const float* __restrict__ bo, float* __restrict__ out)
{
    __shared__ half_t lds[2][2][128 * 32];
    const int tid = threadIdx.x, w = tid >> 6, lane = tid & 63;
    const int l15 = lane & 15, lhi = lane >> 4;
    const int wm = w >> 1, wn = w & 1;
    const int m0 = blockIdx.y * 128, n0 = blockIdx.x * 128;

    const int r0 = w * 32 + (lane >> 2);
    const int r1 = r0 + 16;
    const int u  = lane & 3;
    const size_t gA0 = (size_t)(m0 + r0) * 1024 + u * 8;
    const size_t gA1 = (size_t)(m0 + r1) * 1024 + u * 8;
    const size_t gB0 = (size_t)(n0 + r0) * 1024 + u * 8;
    const size_t gB1 = (size_t)(n0 + r1) * 1024 + u * 8;
    const int d0 = r0 * 32 + ((u ^ ((r0 >> 1) & 3)) * 8);
    const int d1 = r1 * 32 + ((u ^ ((r1 >> 1) & 3)) * 8);

    int4 st[4];
    auto LOAD = [&](int kb) {
        st[0] = *(const int4*)&z[gA0 + kb];
        st[1] = *(const int4*)&z[gA1 + kb];
        st[2] = *(const int4*)&woT[gB0 + kb];
        st[3] = *(const int4*)&woT[gB1 + kb];
    };
    auto WRITE = [&](int bf) {
        *(int4*)&lds[bf][0][d0] = st[0];
        *(int4*)&lds[bf][0][d1] = st[1];
        *(int4*)&lds[bf][1][d0] = st[2];
        *(int4*)&lds[bf][1][d1] = st[3];
    };

    f32x4 acc[4][4] = {};
    LOAD(0); WRITE(0); __syncthreads();
    int cur = 0;
    for (int ks = 0; ks < 32; ++ks) {
        if (ks < 31) LOAD((ks + 1) * 32);
        f16x8 fa[4], fb[4];
        #pragma unroll
        for (int i = 0; i < 4; ++i) {
            const int ra = wm * 64 + i * 16 + l15;
            fa[i] = *(const f16x8*)&lds[cur][0][ra * 32 + ((lhi ^ ((ra >> 1) & 3)) * 8)];
            const int rb = wn * 64 + i * 16 + l15;
            fb[i] = *(const f16x8*)&lds[cur][1][rb * 32 + ((lhi ^ ((rb >> 1) & 3)) * 8)];
        }
        #pragma unroll
        for (int mi = 0; mi < 4; ++mi)
            #pragma unroll
            for (int ni = 0; ni < 4; ++ni)
                acc[mi][ni] = MFMA16(fa[mi], fb[ni], acc[mi][ni]);
        if (ks < 31) WRITE(cur ^ 1);
        __syncthreads();
        cur ^= 1;
    }

    #pragma unroll
    for (int ni = 0; ni < 4; ++ni) {
        const int n = n0 + wn * 64 + ni * 16 + l15;
        const float bb = bo[n];
        #pragma unroll
        for (int mi = 0; mi < 4; ++mi)
            #pragma unroll
            for (int r = 0; r < 4; ++r) {
                const int m = m0 + wm * 64 + mi * 16 + lhi * 4 + r;
                out[(size_t)m * 1024 + n] = acc[mi][ni][r] + bb;
            }
    }
}

// ---------------------------------------------------------------------------
extern "C" void kernel_launch(void* const* d_in, const int* in_sizes, int n_in,
                              void* d_out, int out_size, void* d_ws, size_t ws_size,
                              hipStream_t stream) {
    const float* x  = (const float*)d_in[0];
    const float* Wq = (const float*)d_in[1];
    const float* bq = (const float*)d_in[2];
    const float* Wk = (const float*)d_in[3];
    const float* bk = (const float*)d_in[4];
    const float* Wv = (const float*)d_in[5];
    const float* bv = (const float*)d_in[6];
    const float* Wo = (const float*)d_in[7];
    const float* bo = (const float*)d_in[8];

    float* out      = (float*)d_out;
    float* attn_out = out;
    float* pattern  = out + (size_t)8192 * 1024;

    char* wsb = (char*)d_ws;
    const size_t M16 = 16777216;
    half_t* qh  = (half_t*)(wsb + 0 * M16);
    half_t* ql  = (half_t*)(wsb + 1 * M16);
    half_t* kh  = (half_t*)(wsb + 2 * M16);
    half_t* kl  = (half_t*)(wsb + 3 * M16);
    half_t* vT  = (half_t*)(wsb + 4 * M16);
    half_t* xh  = (half_t*)(wsb + 5 * M16);
    half_t* xl  = (half_t*)(wsb + 6 * M16);
    half_t* wh  = (half_t*)(wsb + 7 * M16);                 // 6 MiB
    half_t* wl  = (half_t*)(wsb + 7 * M16 + 6291456);       // 6 MiB
    half_t* woT = (half_t*)(wsb + 7 * M16 + 12582912);      // 2 MiB
    half_t* zbuf = xh;                                      // alias, dead after k_proj

    k_conv_x <<<4096, 256, 0, stream>>>(x, xh, xl);
    k_conv_w <<<768,  256, 0, stream>>>(Wq, Wk, Wv, wh, wl);
    k_conv_wo<<<256,  256, 0, stream>>>(Wo, woT);
    k_proj   <<<dim3(24, 64), 256, 0, stream>>>(xh, xl, wh, wl, bq, bk, bv,
                                                qh, ql, kh, kl, vT);
    k_attn   <<<dim3(32, 64), 256, 0, stream>>>(qh, ql, kh, kl, vT,
                                                pattern, zbuf);
    k_oproj  <<<dim3(8, 64),  256, 0, stream>>>(zbuf, woT, bo, attn_out);
}

// Round 7
// 1011.508 us; speedup vs baseline: 1.4362x; 1.4362x over previous
//
#include <hip/hip_runtime.h>
#include <hip/hip_bf16.h>

// B=4, S=2048, D_MODEL=1024, H=16, E=64, M=8192 rows, bh = b*16+h (64)
// Precision: fp32 value = hi + lo (2x fp16, ~24 mantissa bits, fp32-exact).
// Products via 3 MFMA passes (hh, hl, lh); ll ~ 2^-24 rel -> dropped.
// V path and PV/O GEMMs: single-pass fp16 (error << thresholds).
// MFMA shape: mfma_f32_16x16x32_f16.
//   A-frag: lane l holds A[m=l&15][k=(l>>4)*8+j]  (16B contiguous)
//   B-frag: lane l holds B[k=(l>>4)*8+j][n=l&15]  (read from [n][k]-major array)
//   C/D  : lane l holds D[row=(l>>4)*4+r][col=l&15]

typedef _Float16 half_t;
typedef __attribute__((ext_vector_type(8))) _Float16 f16x8;
typedef __attribute__((ext_vector_type(4))) _Float16 f16x4;
typedef __attribute__((ext_vector_type(4))) float f32x4;

#define MFMA16(a, b, c) __builtin_amdgcn_mfma_f32_16x16x32_f16(a, b, c, 0, 0, 0)

__device__ __forceinline__ void split2(float v, half_t& h, half_t& l) {
    h = (half_t)v;
    l = (half_t)(v - (float)h);
}

// ---------------------------------------------------------------------------
// x [8192][1024] fp32 -> xh, xl fp16 planes
// ---------------------------------------------------------------------------
__global__ __launch_bounds__(256) void k_conv_x(
    const float* __restrict__ x, half_t* __restrict__ xh, half_t* __restrict__ xl)
{
    const size_t i = ((size_t)blockIdx.x * 256 + threadIdx.x) * 8;
    float4 a = *(const float4*)&x[i];
    float4 b = *(const float4*)&x[i + 4];
    float v[8] = {a.x, a.y, a.z, a.w, b.x, b.y, b.z, b.w};
    f16x8 H, L;
    #pragma unroll
    for (int j = 0; j < 8; ++j) {
        half_t hh, hl; split2(v[j], hh, hl);
        H[j] = hh; L[j] = hl;
    }
    *(f16x8*)&xh[i] = H;
    *(f16x8*)&xl[i] = L;
}

// ---------------------------------------------------------------------------
// W_{Q,K,V} [16][1024 d][64 e] fp32 -> wh, wl fp16 [n=3072][k=1024] (transposed)
// ---------------------------------------------------------------------------
__global__ __launch_bounds__(256) void k_conv_w(
    const float* __restrict__ Wq, const float* __restrict__ Wk, const float* __restrict__ Wv,
    half_t* __restrict__ wh, half_t* __restrict__ wl)
{
    const int bid = blockIdx.x;
    const int mat = bid >> 8, h = (bid >> 4) & 15, dt = bid & 15;
    const float* W = (mat == 0) ? Wq : (mat == 1) ? Wk : Wv;
    __shared__ float t[64][65];
    const int tid = threadIdx.x;
    #pragma unroll
    for (int rep = 0; rep < 4; ++rep) {
        int idx = tid + rep * 256;
        int r = idx >> 4, c4 = (idx & 15) * 4;
        float4 v4 = *(const float4*)&W[(size_t)h * 65536 + (size_t)(dt * 64 + r) * 64 + c4];
        t[r][c4 + 0] = v4.x; t[r][c4 + 1] = v4.y;
        t[r][c4 + 2] = v4.z; t[r][c4 + 3] = v4.w;
    }
    __syncthreads();
    #pragma unroll
    for (int rep = 0; rep < 4; ++rep) {
        int idx = tid + rep * 256;
        int e = idx >> 4, g = (idx & 15) * 4;
        size_t o = ((size_t)(mat * 1024 + h * 64 + e)) * 1024 + dt * 64 + g;
        #pragma unroll
        for (int j = 0; j < 4; ++j) {
            half_t hh, hl; split2(t[g + j][e], hh, hl);
            wh[o + j] = hh; wl[o + j] = hl;
        }
    }
}

// W_O [1024 hd][1024 dm] fp32 -> woT fp16 [dm][hd]
__global__ __launch_bounds__(256) void k_conv_wo(
    const float* __restrict__ Wo, half_t* __restrict__ woT)
{
    const int bi = blockIdx.x >> 4, bj = blockIdx.x & 15;
    __shared__ float t[64][65];
    const int tid = threadIdx.x;
    #pragma unroll
    for (int rep = 0; rep < 4; ++rep) {
        int idx = tid + rep * 256;
        int r = idx >> 4, c4 = (idx & 15) * 4;
        float4 v4 = *(const float4*)&Wo[(size_t)(bi * 64 + r) * 1024 + bj * 64 + c4];
        t[r][c4 + 0] = v4.x; t[r][c4 + 1] = v4.y;
        t[r][c4 + 2] = v4.z; t[r][c4 + 3] = v4.w;
    }
    __syncthreads();
    #pragma unroll
    for (int rep = 0; rep < 4; ++rep) {
        int idx = tid + rep * 256;
        int dm = idx >> 4, g = (idx & 15) * 4;
        size_t o = (size_t)(bj * 64 + dm) * 1024 + bi * 64 + g;
        #pragma unroll
        for (int j = 0; j < 4; ++j)
            woT[o + j] = (half_t)t[g + j][dm];
    }
}

// ---------------------------------------------------------------------------
// QKV projection GEMM: M=8192, N=3072, K=1024.
// Q/K n-blocks: 3-pass fp16-split; V n-blocks (n0>=2048): 1-pass.
// ---------------------------------------------------------------------------
__global__ __launch_bounds__(256) void k_proj(
    const half_t* __restrict__ xh, const half_t* __restrict__ xl,
    const half_t* __restrict__ wh, const half_t* __restrict__ wl,
    const float* __restrict__ bq, const float* __restrict__ bk, const float* __restrict__ bv,
    half_t* __restrict__ oqh, half_t* __restrict__ oql,
    half_t* __restrict__ okh, half_t* __restrict__ okl,
    half_t* __restrict__ ovT)
{
    __shared__ half_t lds[2][4][128 * 32];
    const int tid = threadIdx.x, w = tid >> 6, lane = tid & 63;
    const int l15 = lane & 15, lhi = lane >> 4;
    const int wm = w >> 1, wn = w & 1;
    const int m0 = blockIdx.y * 128, n0 = blockIdx.x * 128;
    const bool isv = (n0 >= 2048);          // V block: single-pass

    const int r0 = w * 32 + (lane >> 2);
    const int r1 = r0 + 16;
    const int u  = lane & 3;
    const size_t gA0 = (size_t)(m0 + r0) * 1024 + u * 8;
    const size_t gA1 = (size_t)(m0 + r1) * 1024 + u * 8;
    const size_t gB0 = (size_t)(n0 + r0) * 1024 + u * 8;
    const size_t gB1 = (size_t)(n0 + r1) * 1024 + u * 8;
    const int d0 = r0 * 32 + ((u ^ ((r0 >> 1) & 3)) * 8);
    const int d1 = r1 * 32 + ((u ^ ((r1 >> 1) & 3)) * 8);

    int4 st[8];
    auto LOAD = [&](int kb) {
        st[0] = *(const int4*)&xh[gA0 + kb];
        st[1] = *(const int4*)&xh[gA1 + kb];
        st[4] = *(const int4*)&wh[gB0 + kb];
        st[5] = *(const int4*)&wh[gB1 + kb];
        if (!isv) {
            st[2] = *(const int4*)&xl[gA0 + kb];
            st[3] = *(const int4*)&xl[gA1 + kb];
            st[6] = *(const int4*)&wl[gB0 + kb];
            st[7] = *(const int4*)&wl[gB1 + kb];
        }
    };
    auto WRITE = [&](int bf) {
        *(int4*)&lds[bf][0][d0] = st[0];
        *(int4*)&lds[bf][0][d1] = st[1];
        *(int4*)&lds[bf][2][d0] = st[4];
        *(int4*)&lds[bf][2][d1] = st[5];
        if (!isv) {
            *(int4*)&lds[bf][1][d0] = st[2];
            *(int4*)&lds[bf][1][d1] = st[3];
            *(int4*)&lds[bf][3][d0] = st[6];
            *(int4*)&lds[bf][3][d1] = st[7];
        }
    };

    f32x4 acc[4][4] = {};

    LOAD(0); WRITE(0); __syncthreads();
    int cur = 0;
    for (int ks = 0; ks < 32; ++ks) {
        if (ks < 31) LOAD((ks + 1) * 32);
        f16x8 fah[4], fal[4], fbh[4], fbl[4];
        #pragma unroll
        for (int i = 0; i < 4; ++i) {
            const int ra = wm * 64 + i * 16 + l15;
            const int aa = ra * 32 + ((lhi ^ ((ra >> 1) & 3)) * 8);
            fah[i] = *(const f16x8*)&lds[cur][0][aa];
            const int rb = wn * 64 + i * 16 + l15;
            const int ab = rb * 32 + ((lhi ^ ((rb >> 1) & 3)) * 8);
            fbh[i] = *(const f16x8*)&lds[cur][2][ab];
            if (!isv) {
                fal[i] = *(const f16x8*)&lds[cur][1][aa];
                fbl[i] = *(const f16x8*)&lds[cur][3][ab];
            }
        }
        if (isv) {
            #pragma unroll
            for (int mi = 0; mi < 4; ++mi)
                #pragma unroll
                for (int ni = 0; ni < 4; ++ni)
                    acc[mi][ni] = MFMA16(fah[mi], fbh[ni], acc[mi][ni]);
        } else {
            #pragma unroll
            for (int mi = 0; mi < 4; ++mi)
                #pragma unroll
                for (int ni = 0; ni < 4; ++ni) {
                    acc[mi][ni] = MFMA16(fah[mi], fbh[ni], acc[mi][ni]);
                    acc[mi][ni] = MFMA16(fah[mi], fbl[ni], acc[mi][ni]);
                    acc[mi][ni] = MFMA16(fal[mi], fbh[ni], acc[mi][ni]);
                }
        }
        if (ks < 31) WRITE(cur ^ 1);
        __syncthreads();
        cur ^= 1;
    }

    #pragma unroll
    for (int ni = 0; ni < 4; ++ni) {
        const int n = n0 + wn * 64 + ni * 16 + l15;
        const int mat = n >> 10, nn = n & 1023;
        const int h = nn >> 6, e = nn & 63;
        const float bias = (mat == 0 ? bq : mat == 1 ? bk : bv)[h * 64 + e];
        #pragma unroll
        for (int mi = 0; mi < 4; ++mi)
            #pragma unroll
            for (int r = 0; r < 4; ++r) {
                const int m = m0 + wm * 64 + mi * 16 + lhi * 4 + r;
                const int b = m >> 11, s = m & 2047;
                const int bh_i = b * 16 + h;
                const float v = acc[mi][ni][r] + bias;
                if (mat == 2) {
                    ovT[((size_t)bh_i * 64 + e) * 2048 + s] = (half_t)v;
                } else {
                    half_t hh, hl; split2(v, hh, hl);
                    const size_t o = ((size_t)bh_i * 2048 + s) * 64 + e;
                    if (mat == 0) { oqh[o] = hh; oql[o] = hl; }
                    else          { okh[o] = hh; okl[o] = hl; }
                }
            }
    }
}

// ---------------------------------------------------------------------------
// Fused attention, recompute flavor, 128 q-rows/block, 512 threads (8 waves).
// Phase A: QK^T 3-pass MFMA per k-tile, online (m,l) in registers only.
// Phase B: recompute QK^T, p = exp(s-m)*inv, bounce fp16 p through swizzled
//          LDS -> coalesced fp32 pattern write + PV A-frags; V staged in LDS
//          (double-buffered, prefetched) so PV B-frags never touch global.
// LDS: kst 32KB + vst 16KB + pa 16KB = 64KB -> 2 blocks/CU (16 waves).
// ---------------------------------------------------------------------------
__global__ __launch_bounds__(512, 4) void k_attn(
    const half_t* __restrict__ qh, const half_t* __restrict__ ql,
    const half_t* __restrict__ kh, const half_t* __restrict__ kl,
    const half_t* __restrict__ vT,
    float* __restrict__ pattern, half_t* __restrict__ z)
{
    __shared__ half_t kst[2][2][64 * 64];   // [buf][hi/lo][swizzled] 32 KB
    __shared__ half_t vst[2][64 * 64];      // [buf][e][key swizzled]  16 KB
    __shared__ half_t pa[128 * 64];         // swizzled p tile, 16 KB

    const int qt = 15 - blockIdx.x, bh = blockIdx.y;
    const int b = bh >> 4, h = bh & 15;
    const int tid = threadIdx.x, w = tid >> 6, lane = tid & 63;
    const int l15 = lane & 15, lhi = lane >> 4;
    const int q0 = qt * 128, rw = q0 + w * 16;
    const int ktmax = 2 * qt + 2;

    // Q fragments (persist both phases)
    const size_t qrow = ((size_t)bh * 2048 + rw + l15) * 64;
    f16x8 aqh[2], aql[2];
    #pragma unroll
    for (int ch = 0; ch < 2; ++ch) {
        aqh[ch] = *(const f16x8*)&qh[qrow + ch * 32 + lhi * 8];
        aql[ch] = *(const f16x8*)&ql[qrow + ch * 32 + lhi * 8];
    }

    // staging: 512 threads, thread covers row sr (0..63), 16B slot su
    const int sr = w * 8 + (lane >> 3);
    const int su = lane & 7;
    const size_t kbase = (size_t)bh * 2048 * 64;
    const size_t vbase = (size_t)bh * 64 * 2048;
    const int sd = sr * 64 + ((su ^ (sr & 7)) * 8);

    int4 stk0, stk1, stv;
    auto LOADK = [&](int kt) {
        const size_t g = kbase + (size_t)(kt * 64 + sr) * 64 + su * 8;
        stk0 = *(const int4*)&kh[g];
        stk1 = *(const int4*)&kl[g];
    };
    auto LOADV = [&](int kt) {
        stv = *(const int4*)&vT[vbase + (size_t)sr * 2048 + kt * 64 + su * 8];
    };
    auto WRITEK = [&](int bf) {
        *(int4*)&kst[bf][0][sd] = stk0;
        *(int4*)&kst[bf][1][sd] = stk1;
    };
    auto WRITEV = [&](int bf) {
        *(int4*)&vst[bf][sd] = stv;
    };
    // QK^T for one staged tile -> acc (scaled + masked, unconditional mask)
    auto QKTILE = [&](int cur, int kt, f32x4* acc) {
        #pragma unroll
        for (int nt = 0; nt < 4; ++nt) {
            const int kr = nt * 16 + l15;
            #pragma unroll
            for (int ch = 0; ch < 2; ++ch) {
                const int slot = ch * 4 + lhi;
                const int ad = kr * 64 + ((slot ^ (kr & 7)) * 8);
                f16x8 bh8 = *(const f16x8*)&kst[cur][0][ad];
                f16x8 bl8 = *(const f16x8*)&kst[cur][1][ad];
                acc[nt] = MFMA16(aqh[ch], bh8, acc[nt]);
                acc[nt] = MFMA16(aqh[ch], bl8, acc[nt]);
                acc[nt] = MFMA16(aql[ch], bh8, acc[nt]);
            }
        }
        #pragma unroll
        for (int nt = 0; nt < 4; ++nt) {
            const int key = kt * 64 + nt * 16 + l15;
            #pragma unroll
            for (int r = 0; r < 4; ++r) {
                float s = acc[nt][r] * 0.125f;
                const int row = rw + lhi * 4 + r;
                if (key > row) s = -1e30f;
                acc[nt][r] = s;
            }
        }
    };

    float m[4], l[4];
    #pragma unroll
    for (int r = 0; r < 4; ++r) { m[r] = -1e30f; l[r] = 0.f; }

    // ---- Phase A: stats only ----
    LOADK(0); WRITEK(0); __syncthreads();
    int cur = 0;
    for (int kt = 0; kt < ktmax; ++kt) {
        if (kt + 1 < ktmax) LOADK(kt + 1);
        f32x4 acc[4] = {};
        QKTILE(cur, kt, acc);
        float tmax[4] = {-1e30f, -1e30f, -1e30f, -1e30f};
        #pragma unroll
        for (int nt = 0; nt < 4; ++nt)
            #pragma unroll
            for (int r = 0; r < 4; ++r)
                tmax[r] = fmaxf(tmax[r], acc[nt][r]);
        #pragma unroll
        for (int off = 1; off < 16; off <<= 1)
            #pragma unroll
            for (int r = 0; r < 4; ++r)
                tmax[r] = fmaxf(tmax[r], __shfl_xor(tmax[r], off));
        float esum[4] = {0.f, 0.f, 0.f, 0.f};
        #pragma unroll
        for (int nt = 0; nt < 4; ++nt)
            #pragma unroll
            for (int r = 0; r < 4; ++r)
                esum[r] += __expf(acc[nt][r] - tmax[r]);
        #pragma unroll
        for (int off = 1; off < 16; off <<= 1)
            #pragma unroll
            for (int r = 0; r < 4; ++r)
                esum[r] += __shfl_xor(esum[r], off);
        #pragma unroll
        for (int r = 0; r < 4; ++r) {
            const float mn = fmaxf(m[r], tmax[r]);
            l[r] = l[r] * __expf(m[r] - mn) + esum[r] * __expf(tmax[r] - mn);
            m[r] = mn;
        }
        if (kt + 1 < ktmax) WRITEK(cur ^ 1);
        __syncthreads();
        cur ^= 1;
    }

    float inv[4];
    #pragma unroll
    for (int r = 0; r < 4; ++r) inv[r] = 1.f / l[r];

    // ---- Phase B: recompute + emit ----
    const int r_    = tid >> 4;            // 0..31
    const int c0    = (tid & 15) * 4;      // streaming col (floats)
    const int chunk = c0 >> 3;
    const int cin   = c0 & 7;
    const int arow  = w * 16 + l15;        // A-frag row (0..127)
    const size_t prow_base = ((size_t)bh * 2048 + q0) * 2048;

    f32x4 acc2[4] = {};
    LOADK(0); LOADV(0); WRITEK(0); WRITEV(0); __syncthreads();
    cur = 0;
    for (int kt = 0; kt < 32; ++kt) {
        if (kt < ktmax) {
            if (kt + 1 < ktmax) { LOADK(kt + 1); LOADV(kt + 1); }
            f32x4 acc[4] = {};
            QKTILE(cur, kt, acc);
            // p = exp(s - m) * inv -> swizzled fp16 pa
            #pragma unroll
            for (int nt = 0; nt < 4; ++nt) {
                const int col = nt * 16 + l15;
                const int cc = col >> 3, ci = col & 7;
                #pragma unroll
                for (int r = 0; r < 4; ++r) {
                    const int row = w * 16 + lhi * 4 + r;
                    const float p = __expf(acc[nt][r] - m[r]) * inv[r];
                    pa[row * 64 + ((cc ^ (row & 7)) * 8) + ci] = (half_t)p;
                }
            }
            __syncthreads();   // pa + (first iter) staging ready
            // PV MFMA: A-frags from pa, B-frags from vst (LDS)
            #pragma unroll
            for (int ch = 0; ch < 2; ++ch) {
                const int slot = ch * 4 + lhi;
                f16x8 af = *(const f16x8*)&pa[arow * 64 + ((slot ^ (arow & 7)) * 8)];
                #pragma unroll
                for (int nt = 0; nt < 4; ++nt) {
                    const int er = nt * 16 + l15;
                    f16x8 bf8 = *(const f16x8*)&vst[cur][er * 64 + ((slot ^ (er & 7)) * 8)];
                    acc2[nt] = MFMA16(af, bf8, acc2[nt]);
                }
            }
            // coalesced fp32 pattern write from pa
            #pragma unroll
            for (int rep = 0; rep < 4; ++rep) {
                const int row = rep * 32 + r_;
                f16x4 pv4 = *(const f16x4*)&pa[row * 64 + ((chunk ^ (row & 7)) * 8) + cin];
                float4 p;
                p.x = (float)pv4[0]; p.y = (float)pv4[1];
                p.z = (float)pv4[2]; p.w = (float)pv4[3];
                *(float4*)&pattern[prow_base + (size_t)row * 2048 + kt * 64 + c0] = p;
            }
            if (kt + 1 < ktmax) { WRITEK(cur ^ 1); WRITEV(cur ^ 1); }
            __syncthreads();   // next staging ready; pa reads done
            cur ^= 1;
        } else {
            float4 zz; zz.x = 0.f; zz.y = 0.f; zz.z = 0.f; zz.w = 0.f;
            #pragma unroll
            for (int rep = 0; rep < 4; ++rep) {
                const int row = rep * 32 + r_;
                *(float4*)&pattern[prow_base + (size_t)row * 2048 + kt * 64 + c0] = zz;
            }
        }
    }

    #pragma unroll
    for (int nt = 0; nt < 4; ++nt) {
        const int e = nt * 16 + l15;
        #pragma unroll
        for (int r = 0; r < 4; ++r) {
            const int row = rw + lhi * 4 + r;
            z[((size_t)(b * 2048 + row)) * 1024 + h * 64 + e] = (half_t)acc2[nt][r];
        }
    }
}

// ---------------------------------------------------------------------------
// O projection GEMM: M=8192, N=1024, K=1024, 1-pass fp16 MFMA.
// ---------------------------------------------------------------------------
__global__ __launch_bounds__(256) void k_oproj(
    const half_t* __restrict__ z, const half_t* __restrict__ woT,
    const float* __restrict__ bo, float* __restrict__ out)
{
    __shared__ half_t lds[2][2][128 * 32];
    const int tid = threadIdx.x, w = tid >> 6, lane = tid & 63;
    const int l15 = lane & 15, lhi = lane >> 4;
    const int wm = w >> 1, wn = w & 1;
    const int m0 = blockIdx.y * 128, n0 = blockIdx.x * 128;

    const int r0 = w * 32 + (lane >> 2);
    const int r1 = r0 + 16;
    const int u  = lane & 3;
    const size_t gA0 = (size_t)(m0 + r0) * 1024 + u * 8;
    const size_t gA1 = (size_t)(m0 + r1) * 1024 + u * 8;
    const size_t gB0 = (size_t)(n0 + r0) * 1024 + u * 8;
    const size_t gB1 = (size_t)(n0 + r1) * 1024 + u * 8;
    const int d0 = r0 * 32 + ((u ^ ((r0 >> 1) & 3)) * 8);
    const int d1 = r1 * 32 + ((u ^ ((r1 >> 1) & 3)) * 8);

    int4 st[4];
    auto LOAD = [&](int kb) {
        st[0] = *(const int4*)&z[gA0 + kb];
        st[1] = *(const int4*)&z[gA1 + kb];
        st[2] = *(const int4*)&woT[gB0 + kb];
        st[3] = *(const int4*)&woT[gB1 + kb];
    };
    auto WRITE = [&](int bf) {
        *(int4*)&lds[bf][0][d0] = st[0];
        *(int4*)&lds[bf][0][d1] = st[1];
        *(int4*)&lds[bf][1][d0] = st[2];
        *(int4*)&lds[bf][1][d1] = st[3];
    };

    f32x4 acc[4][4] = {};
    LOAD(0); WRITE(0); __syncthreads();
    int cur = 0;
    for (int ks = 0; ks < 32; ++ks) {
        if (ks < 31) LOAD((ks + 1) * 32);
        f16x8 fa[4], fb[4];
        #pragma unroll
        for (int i = 0; i < 4; ++i) {
            const int ra = wm * 64 + i * 16 + l15;
            fa[i] = *(const f16x8*)&lds[cur][0][ra * 32 + ((lhi ^ ((ra >> 1) & 3)) * 8)];
            const int rb = wn * 64 + i * 16 + l15;
            fb[i] = *(const f16x8*)&lds[cur][1][rb * 32 + ((lhi ^ ((rb >> 1) & 3)) * 8)];
        }
        #pragma unroll
        for (int mi = 0; mi < 4; ++mi)
            #pragma unroll
            for (int ni = 0; ni < 4; ++ni)
                acc[mi][ni] = MFMA16(fa[mi], fb[ni], acc[mi][ni]);
        if (ks < 31) WRITE(cur ^ 1);
        __syncthreads();
        cur ^= 1;
    }

    #pragma unroll
    for (int ni = 0; ni < 4; ++ni) {
        const int n = n0 + wn * 64 + ni * 16 + l15;
        const float bb = bo[n];
        #pragma unroll
        for (int mi = 0; mi < 4; ++mi)
            #pragma unroll
            for (int r = 0; r < 4; ++r) {
                const int m = m0 + wm * 64 + mi * 16 + lhi * 4 + r;
                out[(size_t)m * 1024 + n] = acc[mi][ni][r] + bb;
            }
    }
}

// ---------------------------------------------------------------------------
extern "C" void kernel_launch(void* const* d_in, const int* in_sizes, int n_in,
                              void* d_out, int out_size, void* d_ws, size_t ws_size,
                              hipStream_t stream) {
    const float* x  = (const float*)d_in[0];
    const float* Wq = (const float*)d_in[1];
    const float* bq = (const float*)d_in[2];
    const float* Wk = (const float*)d_in[3];
    const float* bk = (const float*)d_in[4];
    const float* Wv = (const float*)d_in[5];
    const float* bv = (const float*)d_in[6];
    const float* Wo = (const float*)d_in[7];
    const float* bo = (const float*)d_in[8];

    float* out      = (float*)d_out;
    float* attn_out = out;
    float* pattern  = out + (size_t)8192 * 1024;

    char* wsb = (char*)d_ws;
    const size_t M16 = 16777216;
    half_t* qh  = (half_t*)(wsb + 0 * M16);
    half_t* ql  = (half_t*)(wsb + 1 * M16);
    half_t* kh  = (half_t*)(wsb + 2 * M16);
    half_t* kl  = (half_t*)(wsb + 3 * M16);
    half_t* vT  = (half_t*)(wsb + 4 * M16);
    half_t* xh  = (half_t*)(wsb + 5 * M16);
    half_t* xl  = (half_t*)(wsb + 6 * M16);
    half_t* wh  = (half_t*)(wsb + 7 * M16);                 // 6 MiB
    half_t* wl  = (half_t*)(wsb + 7 * M16 + 6291456);       // 6 MiB
    half_t* woT = (half_t*)(wsb + 7 * M16 + 12582912);      // 2 MiB
    half_t* zbuf = xh;                                      // alias, dead after k_proj

    k_conv_x <<<4096, 256, 0, stream>>>(x, xh, xl);
    k_conv_w <<<768,  256, 0, stream>>>(Wq, Wk, Wv, wh, wl);
    k_conv_wo<<<256,  256, 0, stream>>>(Wo, woT);
    k_proj   <<<dim3(24, 64), 256, 0, stream>>>(xh, xl, wh, wl, bq, bk, bv,
                                                qh, ql, kh, kl, vT);
    k_attn   <<<dim3(16, 64), 512, 0, stream>>>(qh, ql, kh, kl, vT,
                                                pattern, zbuf);
    k_oproj  <<<dim3(8, 64),  256, 0, stream>>>(zbuf, woT, bo, attn_out);
}

// Round 9
// 841.712 us; speedup vs baseline: 1.7259x; 1.2017x over previous
//
#include <hip/hip_runtime.h>
#include <hip/hip_bf16.h>

// B=4, S=2048, D_MODEL=1024, H=16, E=64, M=8192 rows, bh = b*16+h (64)
// Precision: fp32 value = hi + lo (2x fp16, ~24 mantissa bits, fp32-exact).
// Products via 3 MFMA passes (hh, hl, lh); ll ~ 2^-24 rel -> dropped.
// V path and PV/O GEMMs: single-pass fp16 (error << thresholds).
// MFMA shape: mfma_f32_16x16x32_f16.
//   A-frag: lane l holds A[m=l&15][k=(l>>4)*8+j]  (16B contiguous)
//   B-frag: lane l holds B[k=(l>>4)*8+j][n=l&15]  (read from [n][k]-major array)
//   C/D  : lane l holds D[row=(l>>4)*4+r][col=l&15]

typedef _Float16 half_t;
typedef __attribute__((ext_vector_type(8))) _Float16 f16x8;
typedef __attribute__((ext_vector_type(4))) _Float16 f16x4;
typedef __attribute__((ext_vector_type(4))) float f32x4;

#define MFMA16(a, b, c) __builtin_amdgcn_mfma_f32_16x16x32_f16(a, b, c, 0, 0, 0)

__device__ __forceinline__ void split2(float v, half_t& h, half_t& l) {
    h = (half_t)v;
    l = (half_t)(v - (float)h);
}

// ---------------------------------------------------------------------------
// x [8192][1024] fp32 -> xh, xl fp16 planes
// ---------------------------------------------------------------------------
__global__ __launch_bounds__(256) void k_conv_x(
    const float* __restrict__ x, half_t* __restrict__ xh, half_t* __restrict__ xl)
{
    const size_t i = ((size_t)blockIdx.x * 256 + threadIdx.x) * 8;
    float4 a = *(const float4*)&x[i];
    float4 b = *(const float4*)&x[i + 4];
    float v[8] = {a.x, a.y, a.z, a.w, b.x, b.y, b.z, b.w};
    f16x8 H, L;
    #pragma unroll
    for (int j = 0; j < 8; ++j) {
        half_t hh, hl; split2(v[j], hh, hl);
        H[j] = hh; L[j] = hl;
    }
    *(f16x8*)&xh[i] = H;
    *(f16x8*)&xl[i] = L;
}

// ---------------------------------------------------------------------------
// W_{Q,K,V} [16][1024 d][64 e] fp32 -> wh, wl fp16 [n=3072][k=1024] (transposed)
// ---------------------------------------------------------------------------
__global__ __launch_bounds__(256) void k_conv_w(
    const float* __restrict__ Wq, const float* __restrict__ Wk, const float* __restrict__ Wv,
    half_t* __restrict__ wh, half_t* __restrict__ wl)
{
    const int bid = blockIdx.x;
    const int mat = bid >> 8, h = (bid >> 4) & 15, dt = bid & 15;
    const float* W = (mat == 0) ? Wq : (mat == 1) ? Wk : Wv;
    __shared__ float t[64][65];
    const int tid = threadIdx.x;
    #pragma unroll
    for (int rep = 0; rep < 4; ++rep) {
        int idx = tid + rep * 256;
        int r = idx >> 4, c4 = (idx & 15) * 4;
        float4 v4 = *(const float4*)&W[(size_t)h * 65536 + (size_t)(dt * 64 + r) * 64 + c4];
        t[r][c4 + 0] = v4.x; t[r][c4 + 1] = v4.y;
        t[r][c4 + 2] = v4.z; t[r][c4 + 3] = v4.w;
    }
    __syncthreads();
    #pragma unroll
    for (int rep = 0; rep < 4; ++rep) {
        int idx = tid + rep * 256;
        int e = idx >> 4, g = (idx & 15) * 4;
        size_t o = ((size_t)(mat * 1024 + h * 64 + e)) * 1024 + dt * 64 + g;
        #pragma unroll
        for (int j = 0; j < 4; ++j) {
            half_t hh, hl; split2(t[g + j][e], hh, hl);
            wh[o + j] = hh; wl[o + j] = hl;
        }
    }
}

// W_O [1024 hd][1024 dm] fp32 -> woT fp16 [dm][hd]
__global__ __launch_bounds__(256) void k_conv_wo(
    const float* __restrict__ Wo, half_t* __restrict__ woT)
{
    const int bi = blockIdx.x >> 4, bj = blockIdx.x & 15;
    __shared__ float t[64][65];
    const int tid = threadIdx.x;
    #pragma unroll
    for (int rep = 0; rep < 4; ++rep) {
        int idx = tid + rep * 256;
        int r = idx >> 4, c4 = (idx & 15) * 4;
        float4 v4 = *(const float4*)&Wo[(size_t)(bi * 64 + r) * 1024 + bj * 64 + c4];
        t[r][c4 + 0] = v4.x; t[r][c4 + 1] = v4.y;
        t[r][c4 + 2] = v4.z; t[r][c4 + 3] = v4.w;
    }
    __syncthreads();
    #pragma unroll
    for (int rep = 0; rep < 4; ++rep) {
        int idx = tid + rep * 256;
        int dm = idx >> 4, g = (idx & 15) * 4;
        size_t o = (size_t)(bj * 64 + dm) * 1024 + bi * 64 + g;
        #pragma unroll
        for (int j = 0; j < 4; ++j)
            woT[o + j] = (half_t)t[g + j][dm];
    }
}

// ---------------------------------------------------------------------------
// QKV projection GEMM: M=8192, N=3072, K=1024.
// Q/K n-blocks: 3-pass fp16-split; V n-blocks (n0>=2048): 1-pass.
// ---------------------------------------------------------------------------
__global__ __launch_bounds__(256) void k_proj(
    const half_t* __restrict__ xh, const half_t* __restrict__ xl,
    const half_t* __restrict__ wh, const half_t* __restrict__ wl,
    const float* __restrict__ bq, const float* __restrict__ bk, const float* __restrict__ bv,
    half_t* __restrict__ oqh, half_t* __restrict__ oql,
    half_t* __restrict__ okh, half_t* __restrict__ okl,
    half_t* __restrict__ ovT)
{
    __shared__ half_t lds[2][4][128 * 32];
    const int tid = threadIdx.x, w = tid >> 6, lane = tid & 63;
    const int l15 = lane & 15, lhi = lane >> 4;
    const int wm = w >> 1, wn = w & 1;
    const int m0 = blockIdx.y * 128, n0 = blockIdx.x * 128;
    const bool isv = (n0 >= 2048);          // V block: single-pass

    const int r0 = w * 32 + (lane >> 2);
    const int r1 = r0 + 16;
    const int u  = lane & 3;
    const size_t gA0 = (size_t)(m0 + r0) * 1024 + u * 8;
    const size_t gA1 = (size_t)(m0 + r1) * 1024 + u * 8;
    const size_t gB0 = (size_t)(n0 + r0) * 1024 + u * 8;
    const size_t gB1 = (size_t)(n0 + r1) * 1024 + u * 8;
    const int d0 = r0 * 32 + ((u ^ ((r0 >> 1) & 3)) * 8);
    const int d1 = r1 * 32 + ((u ^ ((r1 >> 1) & 3)) * 8);

    int4 st[8];
    auto LOAD = [&](int kb) {
        st[0] = *(const int4*)&xh[gA0 + kb];
        st[1] = *(const int4*)&xh[gA1 + kb];
        st[4] = *(const int4*)&wh[gB0 + kb];
        st[5] = *(const int4*)&wh[gB1 + kb];
        if (!isv) {
            st[2] = *(const int4*)&xl[gA0 + kb];
            st[3] = *(const int4*)&xl[gA1 + kb];
            st[6] = *(const int4*)&wl[gB0 + kb];
            st[7] = *(const int4*)&wl[gB1 + kb];
        }
    };
    auto WRITE = [&](int bf) {
        *(int4*)&lds[bf][0][d0] = st[0];
        *(int4*)&lds[bf][0][d1] = st[1];
        *(int4*)&lds[bf][2][d0] = st[4];
        *(int4*)&lds[bf][2][d1] = st[5];
        if (!isv) {
            *(int4*)&lds[bf][1][d0] = st[2];
            *(int4*)&lds[bf][1][d1] = st[3];
            *(int4*)&lds[bf][3][d0] = st[6];
            *(int4*)&lds[bf][3][d1] = st[7];
        }
    };

    f32x4 acc[4][4] = {};

    LOAD(0); WRITE(0); __syncthreads();
    int cur = 0;
    for (int ks = 0; ks < 32; ++ks) {
        if (ks < 31) LOAD((ks + 1) * 32);
        f16x8 fah[4], fal[4], fbh[4], fbl[4];
        #pragma unroll
        for (int i = 0; i < 4; ++i) {
            const int ra = wm * 64 + i * 16 + l15;
            const int aa = ra * 32 + ((lhi ^ ((ra >> 1) & 3)) * 8);
            fah[i] = *(const f16x8*)&lds[cur][0][aa];
            const int rb = wn * 64 + i * 16 + l15;
            const int ab = rb * 32 + ((lhi ^ ((rb >> 1) & 3)) * 8);
            fbh[i] = *(const f16x8*)&lds[cur][2][ab];
            if (!isv) {
                fal[i] = *(const f16x8*)&lds[cur][1][aa];
                fbl[i] = *(const f16x8*)&lds[cur][3][ab];
            }
        }
        if (isv) {
            #pragma unroll
            for (int mi = 0; mi < 4; ++mi)
                #pragma unroll
                for (int ni = 0; ni < 4; ++ni)
                    acc[mi][ni] = MFMA16(fah[mi], fbh[ni], acc[mi][ni]);
        } else {
            #pragma unroll
            for (int mi = 0; mi < 4; ++mi)
                #pragma unroll
                for (int ni = 0; ni < 4; ++ni) {
                    acc[mi][ni] = MFMA16(fah[mi], fbh[ni], acc[mi][ni]);
                    acc[mi][ni] = MFMA16(fah[mi], fbl[ni], acc[mi][ni]);
                    acc[mi][ni] = MFMA16(fal[mi], fbh[ni], acc[mi][ni]);
                }
        }
        if (ks < 31) WRITE(cur ^ 1);
        __syncthreads();
        cur ^= 1;
    }

    #pragma unroll
    for (int ni = 0; ni < 4; ++ni) {
        const int n = n0 + wn * 64 + ni * 16 + l15;
        const int mat = n >> 10, nn = n & 1023;
        const int h = nn >> 6, e = nn & 63;
        const float bias = (mat == 0 ? bq : mat == 1 ? bk : bv)[h * 64 + e];
        #pragma unroll
        for (int mi = 0; mi < 4; ++mi)
            #pragma unroll
            for (int r = 0; r < 4; ++r) {
                const int m = m0 + wm * 64 + mi * 16 + lhi * 4 + r;
                const int b = m >> 11, s = m & 2047;
                const int bh_i = b * 16 + h;
                const float v = acc[mi][ni][r] + bias;
                if (mat == 2) {
                    ovT[((size_t)bh_i * 64 + e) * 2048 + s] = (half_t)v;
                } else {
                    half_t hh, hl; split2(v, hh, hl);
                    const size_t o = ((size_t)bh_i * 2048 + s) * 64 + e;
                    if (mat == 0) { oqh[o] = hh; oql[o] = hl; }
                    else          { okh[o] = hh; okl[o] = hl; }
                }
            }
    }
}

// ---------------------------------------------------------------------------
// Fused attention, recompute flavor, 128 q-rows/block, 512 threads (8 waves).
// XCD-aware 1D grid: all 16 qt-blocks of a bh land on one XCD (L2 K/V reuse),
// heavy-qt first. Pattern stores are nontemporal (write-once, keep L2 for K/V).
// Phase A: QK^T 3-pass MFMA per k-tile, online (m,l) in registers only.
// Phase B: recompute QK^T, p = exp(s-m)*inv, bounce fp16 p through swizzled
//          LDS -> coalesced fp32 pattern write + PV A-frags; V staged in LDS.
// LDS: kst 32KB + vst 16KB + pa 16KB = 64KB -> 2 blocks/CU (16 waves).
// ---------------------------------------------------------------------------
__global__ __launch_bounds__(512, 4) void k_attn(
    const half_t* __restrict__ qh, const half_t* __restrict__ ql,
    const half_t* __restrict__ kh, const half_t* __restrict__ kl,
    const half_t* __restrict__ vT,
    float* __restrict__ pattern, half_t* __restrict__ z)
{
    __shared__ half_t kst[2][2][64 * 64];   // [buf][hi/lo][swizzled] 32 KB
    __shared__ half_t vst[2][64 * 64];      // [buf][e][key swizzled]  16 KB
    __shared__ half_t pa[128 * 64];         // swizzled p tile, 16 KB

    // XCD-aware decode: xcd = bid&7 == bh&7 (assuming round-robin dispatch)
    const int bid = blockIdx.x;
    const int xcd = bid & 7;
    const int idx = bid >> 3;               // 0..127
    const int bh  = xcd + 8 * (idx & 7);    // 0..63
    const int qt  = 15 - (idx >> 3);        // heavy first
    const int b = bh >> 4, h = bh & 15;
    const int tid = threadIdx.x, w = tid >> 6, lane = tid & 63;
    const int l15 = lane & 15, lhi = lane >> 4;
    const int q0 = qt * 128, rw = q0 + w * 16;
    const int ktmax = 2 * qt + 2;

    // Q fragments (persist both phases)
    const size_t qrow = ((size_t)bh * 2048 + rw + l15) * 64;
    f16x8 aqh[2], aql[2];
    #pragma unroll
    for (int ch = 0; ch < 2; ++ch) {
        aqh[ch] = *(const f16x8*)&qh[qrow + ch * 32 + lhi * 8];
        aql[ch] = *(const f16x8*)&ql[qrow + ch * 32 + lhi * 8];
    }

    // staging: 512 threads, thread covers row sr (0..63), 16B slot su
    const int sr = w * 8 + (lane >> 3);
    const int su = lane & 7;
    const size_t kbase = (size_t)bh * 2048 * 64;
    const size_t vbase = (size_t)bh * 64 * 2048;
    const int sd = sr * 64 + ((su ^ (sr & 7)) * 8);

    int4 stk0, stk1, stv;
    auto LOADK = [&](int kt) {
        const size_t g = kbase + (size_t)(kt * 64 + sr) * 64 + su * 8;
        stk0 = *(const int4*)&kh[g];
        stk1 = *(const int4*)&kl[g];
    };
    auto LOADV = [&](int kt) {
        stv = *(const int4*)&vT[vbase + (size_t)sr * 2048 + kt * 64 + su * 8];
    };
    auto WRITEK = [&](int bf) {
        *(int4*)&kst[bf][0][sd] = stk0;
        *(int4*)&kst[bf][1][sd] = stk1;
    };
    auto WRITEV = [&](int bf) {
        *(int4*)&vst[bf][sd] = stv;
    };
    // QK^T for one staged tile -> acc (scaled + masked, unconditional mask)
    auto QKTILE = [&](int cur, int kt, f32x4* acc) {
        #pragma unroll
        for (int nt = 0; nt < 4; ++nt) {
            const int kr = nt * 16 + l15;
            #pragma unroll
            for (int ch = 0; ch < 2; ++ch) {
                const int slot = ch * 4 + lhi;
                const int ad = kr * 64 + ((slot ^ (kr & 7)) * 8);
                f16x8 bh8 = *(const f16x8*)&kst[cur][0][ad];
                f16x8 bl8 = *(const f16x8*)&kst[cur][1][ad];
                acc[nt] = MFMA16(aqh[ch], bh8, acc[nt]);
                acc[nt] = MFMA16(aqh[ch], bl8, acc[nt]);
                acc[nt] = MFMA16(aql[ch], bh8, acc[nt]);
            }
        }
        #pragma unroll
        for (int nt = 0; nt < 4; ++nt) {
            const int key = kt * 64 + nt * 16 + l15;
            #pragma unroll
            for (int r = 0; r < 4; ++r) {
                float s = acc[nt][r] * 0.125f;
                const int row = rw + lhi * 4 + r;
                if (key > row) s = -1e30f;
                acc[nt][r] = s;
            }
        }
    };

    float m[4], l[4];
    #pragma unroll
    for (int r = 0; r < 4; ++r) { m[r] = -1e30f; l[r] = 0.f; }

    // ---- Phase A: stats only ----
    LOADK(0); WRITEK(0); __syncthreads();
    int cur = 0;
    for (int kt = 0; kt < ktmax; ++kt) {
        if (kt + 1 < ktmax) LOADK(kt + 1);
        f32x4 acc[4] = {};
        QKTILE(cur, kt, acc);
        float tmax[4] = {-1e30f, -1e30f, -1e30f, -1e30f};
        #pragma unroll
        for (int nt = 0; nt < 4; ++nt)
            #pragma unroll
            for (int r = 0; r < 4; ++r)
                tmax[r] = fmaxf(tmax[r], acc[nt][r]);
        #pragma unroll
        for (int off = 1; off < 16; off <<= 1)
            #pragma unroll
            for (int r = 0; r < 4; ++r)
                tmax[r] = fmaxf(tmax[r], __shfl_xor(tmax[r], off));
        float esum[4] = {0.f, 0.f, 0.f, 0.f};
        #pragma unroll
        for (int nt = 0; nt < 4; ++nt)
            #pragma unroll
            for (int r = 0; r < 4; ++r)
                esum[r] += __expf(acc[nt][r] - tmax[r]);
        #pragma unroll
        for (int off = 1; off < 16; off <<= 1)
            #pragma unroll
            for (int r = 0; r < 4; ++r)
                esum[r] += __shfl_xor(esum[r], off);
        #pragma unroll
        for (int r = 0; r < 4; ++r) {
            const float mn = fmaxf(m[r], tmax[r]);
            l[r] = l[r] * __expf(m[r] - mn) + esum[r] * __expf(tmax[r] - mn);
            m[r] = mn;
        }
        if (kt + 1 < ktmax) WRITEK(cur ^ 1);
        __syncthreads();
        cur ^= 1;
    }

    float inv[4];
    #pragma unroll
    for (int r = 0; r < 4; ++r) inv[r] = 1.f / l[r];

    // ---- Phase B: recompute + emit ----
    const int r_    = tid >> 4;            // 0..31
    const int c0    = (tid & 15) * 4;      // streaming col (floats)
    const int chunk = c0 >> 3;
    const int cin   = c0 & 7;
    const int arow  = w * 16 + l15;        // A-frag row (0..127)
    const size_t prow_base = ((size_t)bh * 2048 + q0) * 2048;

    f32x4 acc2[4] = {};
    LOADK(0); LOADV(0); WRITEK(0); WRITEV(0); __syncthreads();
    cur = 0;
    for (int kt = 0; kt < 32; ++kt) {
        if (kt < ktmax) {
            if (kt + 1 < ktmax) { LOADK(kt + 1); LOADV(kt + 1); }
            f32x4 acc[4] = {};
            QKTILE(cur, kt, acc);
            // p = exp(s - m) * inv -> swizzled fp16 pa
            #pragma unroll
            for (int nt = 0; nt < 4; ++nt) {
                const int col = nt * 16 + l15;
                const int cc = col >> 3, ci = col & 7;
                #pragma unroll
                for (int r = 0; r < 4; ++r) {
                    const int row = w * 16 + lhi * 4 + r;
                    const float p = __expf(acc[nt][r] - m[r]) * inv[r];
                    pa[row * 64 + ((cc ^ (row & 7)) * 8) + ci] = (half_t)p;
                }
            }
            __syncthreads();   // pa + staging ready
            // PV MFMA: A-frags from pa, B-frags from vst (LDS)
            #pragma unroll
            for (int ch = 0; ch < 2; ++ch) {
                const int slot = ch * 4 + lhi;
                f16x8 af = *(const f16x8*)&pa[arow * 64 + ((slot ^ (arow & 7)) * 8)];
                #pragma unroll
                for (int nt = 0; nt < 4; ++nt) {
                    const int er = nt * 16 + l15;
                    f16x8 bf8 = *(const f16x8*)&vst[cur][er * 64 + ((slot ^ (er & 7)) * 8)];
                    acc2[nt] = MFMA16(af, bf8, acc2[nt]);
                }
            }
            // coalesced fp32 pattern write from pa (nontemporal)
            #pragma unroll
            for (int rep = 0; rep < 4; ++rep) {
                const int row = rep * 32 + r_;
                f16x4 pv4 = *(const f16x4*)&pa[row * 64 + ((chunk ^ (row & 7)) * 8) + cin];
                f32x4 p;
                p[0] = (float)pv4[0]; p[1] = (float)pv4[1];
                p[2] = (float)pv4[2]; p[3] = (float)pv4[3];
                __builtin_nontemporal_store(p,
                    (f32x4*)&pattern[prow_base + (size_t)row * 2048 + kt * 64 + c0]);
            }
            if (kt + 1 < ktmax) { WRITEK(cur ^ 1); WRITEV(cur ^ 1); }
            __syncthreads();   // next staging ready; pa reads done
            cur ^= 1;
        } else {
            f32x4 zz = {0.f, 0.f, 0.f, 0.f};
            #pragma unroll
            for (int rep = 0; rep < 4; ++rep) {
                const int row = rep * 32 + r_;
                __builtin_nontemporal_store(zz,
                    (f32x4*)&pattern[prow_base + (size_t)row * 2048 + kt * 64 + c0]);
            }
        }
    }

    #pragma unroll
    for (int nt = 0; nt < 4; ++nt) {
        const int e = nt * 16 + l15;
        #pragma unroll
        for (int r = 0; r < 4; ++r) {
            const int row = rw + lhi * 4 + r;
            z[((size_t)(b * 2048 + row)) * 1024 + h * 64 + e] = (half_t)acc2[nt][r];
        }
    }
}

// ---------------------------------------------------------------------------
// O projection GEMM: M=8192, N=1024, K=1024, 1-pass fp16 MFMA.
// ---------------------------------------------------------------------------
__global__ __launch_bounds__(256) void k_oproj(
    const half_t* __restrict__ z, const half_t* __restrict__ woT,
    const float* __restrict__ bo, float* __restrict__ out)
{
    __shared__ half_t lds[2][2][128 * 32];
    const int tid = threadIdx.x, w = tid >> 6, lane = tid & 63;
    const int l15 = lane & 15, lhi = lane >> 4;
    const int wm = w >> 1, wn = w & 1;
    const int m0 = blockIdx.y * 128, n0 = blockIdx.x * 128;

    const int r0 = w * 32 + (lane >> 2);
    const int r1 = r0 + 16;
    const int u  = lane & 3;
    const size_t gA0 = (size_t)(m0 + r0) * 1024 + u * 8;
    const size_t gA1 = (size_t)(m0 + r1) * 1024 + u * 8;
    const size_t gB0 = (size_t)(n0 + r0) * 1024 + u * 8;
    const size_t gB1 = (size_t)(n0 + r1) * 1024 + u * 8;
    const int d0 = r0 * 32 + ((u ^ ((r0 >> 1) & 3)) * 8);
    const int d1 = r1 * 32 + ((u ^ ((r1 >> 1) & 3)) * 8);

    int4 st[4];
    auto LOAD = [&](int kb) {
        st[0] = *(const int4*)&z[gA0 + kb];
        st[1] = *(const int4*)&z[gA1 + kb];
        st[2] = *(const int4*)&woT[gB0 + kb];
        st[3] = *(const int4*)&woT[gB1 + kb];
    };
    auto WRITE = [&](int bf) {
        *(int4*)&lds[bf][0][d0] = st[0];
        *(int4*)&lds[bf][0][d1] = st[1];
        *(int4*)&lds[bf][1][d0] = st[2];
        *(int4*)&lds[bf][1][d1] = st[3];
    };

    f32x4 acc[4][4] = {};
    LOAD(0); WRITE(0); __syncthreads();
    int cur = 0;
    for (int ks = 0; ks < 32; ++ks) {
        if (ks < 31) LOAD((ks + 1) * 32);
        f16x8 fa[4], fb[4];
        #pragma unroll
        for (int i = 0; i < 4; ++i) {
            const int ra = wm * 64 + i * 16 + l15;
            fa[i] = *(const f16x8*)&lds[cur][0][ra * 32 + ((lhi ^ ((ra >> 1) & 3)) * 8)];
            const int rb = wn * 64 + i * 16 + l15;
            fb[i] = *(const f16x8*)&lds[cur][1][rb * 32 + ((lhi ^ ((rb >> 1) & 3)) * 8)];
        }
        #pragma unroll
        for (int mi = 0; mi < 4; ++mi)
            #pragma unroll
            for (int ni = 0; ni < 4; ++ni)
                acc[mi][ni] = MFMA16(fa[mi], fb[ni], acc[mi][ni]);
        if (ks < 31) WRITE(cur ^ 1);
        __syncthreads();
        cur ^= 1;
    }

    #pragma unroll
    for (int ni = 0; ni < 4; ++ni) {
        const int n = n0 + wn * 64 + ni * 16 + l15;
        const float bb = bo[n];
        #pragma unroll
        for (int mi = 0; mi < 4; ++mi)
            #pragma unroll
            for (int r = 0; r < 4; ++r) {
                const int m = m0 + wm * 64 + mi * 16 + lhi * 4 + r;
                __builtin_nontemporal_store(acc[mi][ni][r] + bb,
                                            &out[(size_t)m * 1024 + n]);
            }
    }
}

// ---------------------------------------------------------------------------
extern "C" void kernel_launch(void* const* d_in, const int* in_sizes, int n_in,
                              void* d_out, int out_size, void* d_ws, size_t ws_size,
                              hipStream_t stream) {
    const float* x  = (const float*)d_in[0];
    const float* Wq = (const float*)d_in[1];
    const float* bq = (const float*)d_in[2];
    const float* Wk = (const float*)d_in[3];
    const float* bk = (const float*)d_in[4];
    const float* Wv = (const float*)d_in[5];
    const float* bv = (const float*)d_in[6];
    const float* Wo = (const float*)d_in[7];
    const float* bo = (const float*)d_in[8];

    float* out      = (float*)d_out;
    float* attn_out = out;
    float* pattern  = out + (size_t)8192 * 1024;

    char* wsb = (char*)d_ws;
    const size_t M16 = 16777216;
    half_t* qh  = (half_t*)(wsb + 0 * M16);
    half_t* ql  = (half_t*)(wsb + 1 * M16);
    half_t* kh  = (half_t*)(wsb + 2 * M16);
    half_t* kl  = (half_t*)(wsb + 3 * M16);
    half_t* vT  = (half_t*)(wsb + 4 * M16);
    half_t* xh  = (half_t*)(wsb + 5 * M16);
    half_t* xl  = (half_t*)(wsb + 6 * M16);
    half_t* wh  = (half_t*)(wsb + 7 * M16);                 // 6 MiB
    half_t* wl  = (half_t*)(wsb + 7 * M16 + 6291456);       // 6 MiB
    half_t* woT = (half_t*)(wsb + 7 * M16 + 12582912);      // 2 MiB
    half_t* zbuf = xh;                                      // alias, dead after k_proj

    k_conv_x <<<4096, 256, 0, stream>>>(x, xh, xl);
    k_conv_w <<<768,  256, 0, stream>>>(Wq, Wk, Wv, wh, wl);
    k_conv_wo<<<256,  256, 0, stream>>>(Wo, woT);
    k_proj   <<<dim3(24, 64), 256, 0, stream>>>(xh, xl, wh, wl, bq, bk, bv,
                                                qh, ql, kh, kl, vT);
    k_attn   <<<dim3(1024), 512, 0, stream>>>(qh, ql, kh, kl, vT,
                                              pattern, zbuf);
    k_oproj  <<<dim3(8, 64),  256, 0, stream>>>(zbuf, woT, bo, attn_out);
}

// Round 10
// 534.911 us; speedup vs baseline: 2.7158x; 1.5736x over previous
//
#include <hip/hip_runtime.h>
#include <hip/hip_bf16.h>

// B=4, S=2048, D_MODEL=1024, H=16, E=64, M=8192 rows, bh = b*16+h (64)
// Precision: fp32 value = hi + lo (2x fp16, ~24 mantissa bits, fp32-exact).
// Products via 3 MFMA passes (hh, hl, lh); ll ~ 2^-24 rel -> dropped.
// V path and PV/O GEMMs: single-pass fp16 (error << thresholds).
// MFMA shape: mfma_f32_16x16x32_f16.
//   A-frag: lane l holds A[m=l&15][k=(l>>4)*8+j]  (16B contiguous)
//   B-frag: lane l holds B[k=(l>>4)*8+j][n=l&15]  (read from [n][k]-major array)
//   C/D  : lane l holds D[row=(l>>4)*4+r][col=l&15]

typedef _Float16 half_t;
typedef __attribute__((ext_vector_type(8))) _Float16 f16x8;
typedef __attribute__((ext_vector_type(4))) _Float16 f16x4;
typedef __attribute__((ext_vector_type(4))) float f32x4;

#define MFMA16(a, b, c) __builtin_amdgcn_mfma_f32_16x16x32_f16(a, b, c, 0, 0, 0)

__device__ __forceinline__ void split2(float v, half_t& h, half_t& l) {
    h = (half_t)v;
    l = (half_t)(v - (float)h);
}

// async global->LDS, 16B per lane; LDS dest = wave-uniform base + lane*16
__device__ __forceinline__ void gload_lds16(const half_t* g, half_t* s) {
    __builtin_amdgcn_global_load_lds(
        (const __attribute__((address_space(1))) void*)g,
        (__attribute__((address_space(3))) void*)s, 16, 0, 0);
}

// ---------------------------------------------------------------------------
// x [8192][1024] fp32 -> xh, xl fp16 planes
// ---------------------------------------------------------------------------
__global__ __launch_bounds__(256) void k_conv_x(
    const float* __restrict__ x, half_t* __restrict__ xh, half_t* __restrict__ xl)
{
    const size_t i = ((size_t)blockIdx.x * 256 + threadIdx.x) * 8;
    float4 a = *(const float4*)&x[i];
    float4 b = *(const float4*)&x[i + 4];
    float v[8] = {a.x, a.y, a.z, a.w, b.x, b.y, b.z, b.w};
    f16x8 H, L;
    #pragma unroll
    for (int j = 0; j < 8; ++j) {
        half_t hh, hl; split2(v[j], hh, hl);
        H[j] = hh; L[j] = hl;
    }
    *(f16x8*)&xh[i] = H;
    *(f16x8*)&xl[i] = L;
}

// ---------------------------------------------------------------------------
// W_{Q,K,V} [16][1024 d][64 e] fp32 -> wh, wl fp16 [n=3072][k=1024] (transposed)
// ---------------------------------------------------------------------------
__global__ __launch_bounds__(256) void k_conv_w(
    const float* __restrict__ Wq, const float* __restrict__ Wk, const float* __restrict__ Wv,
    half_t* __restrict__ wh, half_t* __restrict__ wl)
{
    const int bid = blockIdx.x;
    const int mat = bid >> 8, h = (bid >> 4) & 15, dt = bid & 15;
    const float* W = (mat == 0) ? Wq : (mat == 1) ? Wk : Wv;
    __shared__ float t[64][65];
    const int tid = threadIdx.x;
    #pragma unroll
    for (int rep = 0; rep < 4; ++rep) {
        int idx = tid + rep * 256;
        int r = idx >> 4, c4 = (idx & 15) * 4;
        float4 v4 = *(const float4*)&W[(size_t)h * 65536 + (size_t)(dt * 64 + r) * 64 + c4];
        t[r][c4 + 0] = v4.x; t[r][c4 + 1] = v4.y;
        t[r][c4 + 2] = v4.z; t[r][c4 + 3] = v4.w;
    }
    __syncthreads();
    #pragma unroll
    for (int rep = 0; rep < 4; ++rep) {
        int idx = tid + rep * 256;
        int e = idx >> 4, g = (idx & 15) * 4;
        size_t o = ((size_t)(mat * 1024 + h * 64 + e)) * 1024 + dt * 64 + g;
        #pragma unroll
        for (int j = 0; j < 4; ++j) {
            half_t hh, hl; split2(t[g + j][e], hh, hl);
            wh[o + j] = hh; wl[o + j] = hl;
        }
    }
}

// W_O [1024 hd][1024 dm] fp32 -> woT fp16 [dm][hd]
__global__ __launch_bounds__(256) void k_conv_wo(
    const float* __restrict__ Wo, half_t* __restrict__ woT)
{
    const int bi = blockIdx.x >> 4, bj = blockIdx.x & 15;
    __shared__ float t[64][65];
    const int tid = threadIdx.x;
    #pragma unroll
    for (int rep = 0; rep < 4; ++rep) {
        int idx = tid + rep * 256;
        int r = idx >> 4, c4 = (idx & 15) * 4;
        float4 v4 = *(const float4*)&Wo[(size_t)(bi * 64 + r) * 1024 + bj * 64 + c4];
        t[r][c4 + 0] = v4.x; t[r][c4 + 1] = v4.y;
        t[r][c4 + 2] = v4.z; t[r][c4 + 3] = v4.w;
    }
    __syncthreads();
    #pragma unroll
    for (int rep = 0; rep < 4; ++rep) {
        int idx = tid + rep * 256;
        int dm = idx >> 4, g = (idx & 15) * 4;
        size_t o = (size_t)(bj * 64 + dm) * 1024 + bi * 64 + g;
        #pragma unroll
        for (int j = 0; j < 4; ++j)
            woT[o + j] = (half_t)t[g + j][dm];
    }
}

// ---------------------------------------------------------------------------
// QKV projection GEMM: M=8192, N=3072, K=1024.
// Q/K n-blocks: 3-pass fp16-split; V n-blocks (n0>=2048): 1-pass.
// Staging via global_load_lds width=16 (linear LDS dest, pre-swizzled global
// source chunk: src chunk = u ^ ((row>>1)&3); read side XORs the same way).
// One barrier per k-step: prefetch buf^1, compute buf, sync.
// ---------------------------------------------------------------------------
__global__ __launch_bounds__(256) void k_proj(
    const half_t* __restrict__ xh, const half_t* __restrict__ xl,
    const half_t* __restrict__ wh, const half_t* __restrict__ wl,
    const float* __restrict__ bq, const float* __restrict__ bk, const float* __restrict__ bv,
    half_t* __restrict__ oqh, half_t* __restrict__ oql,
    half_t* __restrict__ okh, half_t* __restrict__ okl,
    half_t* __restrict__ ovT)
{
    __shared__ half_t lds[2][4][128 * 32];   // [buf][Ah,Al,Bh,Bl][row*32 + c]
    const int tid = threadIdx.x, w = tid >> 6, lane = tid & 63;
    const int l15 = lane & 15, lhi = lane >> 4;
    const int wm = w >> 1, wn = w & 1;
    const int m0 = blockIdx.y * 128, n0 = blockIdx.x * 128;
    const bool isv = (n0 >= 2048);          // V block: single-pass

    // staging geometry: per plane-half, thread covers row (hh*64 + tid>>2),
    // 16B chunk (tid&3); global chunk pre-swizzled so LDS stays linear.
    const int srow = tid >> 2;              // 0..63 within half
    const int schk = tid & 3;

    auto STAGE = [&](int bf, int kb) {
        #pragma unroll
        for (int p = 0; p < 4; ++p) {
            if (isv && (p & 1)) continue;
            const half_t* gp = (p == 0) ? xh : (p == 1) ? xl : (p == 2) ? wh : wl;
            const int row0g = (p < 2) ? m0 : n0;
            #pragma unroll
            for (int hh = 0; hh < 2; ++hh) {
                const int row = hh * 64 + srow;
                const int swc = schk ^ ((row >> 1) & 3);
                const half_t* src = gp + (size_t)(row0g + row) * 1024 + kb + swc * 8;
                half_t* dst = &lds[bf][p][hh * 2048 + w * 512];   // +lane*8 implicit
                gload_lds16(src, dst);
            }
        }
    };

    f32x4 acc[4][4] = {};

    STAGE(0, 0);
    __syncthreads();
    int cur = 0;
    for (int ks = 0; ks < 32; ++ks) {
        if (ks < 31) STAGE(cur ^ 1, (ks + 1) * 32);
        f16x8 fah[4], fal[4], fbh[4], fbl[4];
        #pragma unroll
        for (int i = 0; i < 4; ++i) {
            const int ra = wm * 64 + i * 16 + l15;
            const int aa = ra * 32 + ((lhi ^ ((ra >> 1) & 3)) * 8);
            fah[i] = *(const f16x8*)&lds[cur][0][aa];
            const int rb = wn * 64 + i * 16 + l15;
            const int ab = rb * 32 + ((lhi ^ ((rb >> 1) & 3)) * 8);
            fbh[i] = *(const f16x8*)&lds[cur][2][ab];
            if (!isv) {
                fal[i] = *(const f16x8*)&lds[cur][1][aa];
                fbl[i] = *(const f16x8*)&lds[cur][3][ab];
            }
        }
        if (isv) {
            #pragma unroll
            for (int mi = 0; mi < 4; ++mi)
                #pragma unroll
                for (int ni = 0; ni < 4; ++ni)
                    acc[mi][ni] = MFMA16(fah[mi], fbh[ni], acc[mi][ni]);
        } else {
            #pragma unroll
            for (int mi = 0; mi < 4; ++mi)
                #pragma unroll
                for (int ni = 0; ni < 4; ++ni) {
                    acc[mi][ni] = MFMA16(fah[mi], fbh[ni], acc[mi][ni]);
                    acc[mi][ni] = MFMA16(fah[mi], fbl[ni], acc[mi][ni]);
                    acc[mi][ni] = MFMA16(fal[mi], fbh[ni], acc[mi][ni]);
                }
        }
        __syncthreads();   // drains vmcnt (buf^1 landed) + all reads of cur done
        cur ^= 1;
    }

    #pragma unroll
    for (int ni = 0; ni < 4; ++ni) {
        const int n = n0 + wn * 64 + ni * 16 + l15;
        const int mat = n >> 10, nn = n & 1023;
        const int h = nn >> 6, e = nn & 63;
        const float bias = (mat == 0 ? bq : mat == 1 ? bk : bv)[h * 64 + e];
        #pragma unroll
        for (int mi = 0; mi < 4; ++mi)
            #pragma unroll
            for (int r = 0; r < 4; ++r) {
                const int m = m0 + wm * 64 + mi * 16 + lhi * 4 + r;
                const int b = m >> 11, s = m & 2047;
                const int bh_i = b * 16 + h;
                const float v = acc[mi][ni][r] + bias;
                if (mat == 2) {
                    ovT[((size_t)bh_i * 64 + e) * 2048 + s] = (half_t)v;
                } else {
                    half_t hh, hl; split2(v, hh, hl);
                    const size_t o = ((size_t)bh_i * 2048 + s) * 64 + e;
                    if (mat == 0) { oqh[o] = hh; oql[o] = hl; }
                    else          { okh[o] = hh; okl[o] = hl; }
                }
            }
    }
}

// ---------------------------------------------------------------------------
// Fused attention, recompute flavor, 128 q-rows/block, 512 threads (8 waves).
// XCD-aware 1D grid: all 16 qt-blocks of a bh land on one XCD (L2 K/V reuse),
// heavy-qt first. Pattern stores are nontemporal (write-once, keep L2 for K/V).
// Phase A: QK^T 3-pass MFMA per k-tile, online (m,l) in registers only.
// Phase B: recompute QK^T, p = exp(s-m)*inv, bounce fp16 p through swizzled
//          LDS -> coalesced fp32 pattern write + PV A-frags; V staged in LDS.
// LDS: kst 32KB + vst 16KB + pa 16KB = 64KB -> 2 blocks/CU (16 waves).
// ---------------------------------------------------------------------------
__global__ __launch_bounds__(512, 4) void k_attn(
    const half_t* __restrict__ qh, const half_t* __restrict__ ql,
    const half_t* __restrict__ kh, const half_t* __restrict__ kl,
    const half_t* __restrict__ vT,
    float* __restrict__ pattern, half_t* __restrict__ z)
{
    __shared__ half_t kst[2][2][64 * 64];   // [buf][hi/lo][swizzled] 32 KB
    __shared__ half_t vst[2][64 * 64];      // [buf][e][key swizzled]  16 KB
    __shared__ half_t pa[128 * 64];         // swizzled p tile, 16 KB

    // XCD-aware decode: xcd = bid&7 == bh&7 (assuming round-robin dispatch)
    const int bid = blockIdx.x;
    const int xcd = bid & 7;
    const int idx = bid >> 3;               // 0..127
    const int bh  = xcd + 8 * (idx & 7);    // 0..63
    const int qt  = 15 - (idx >> 3);        // heavy first
    const int b = bh >> 4, h = bh & 15;
    const int tid = threadIdx.x, w = tid >> 6, lane = tid & 63;
    const int l15 = lane & 15, lhi = lane >> 4;
    const int q0 = qt * 128, rw = q0 + w * 16;
    const int ktmax = 2 * qt + 2;

    // Q fragments (persist both phases)
    const size_t qrow = ((size_t)bh * 2048 + rw + l15) * 64;
    f16x8 aqh[2], aql[2];
    #pragma unroll
    for (int ch = 0; ch < 2; ++ch) {
        aqh[ch] = *(const f16x8*)&qh[qrow + ch * 32 + lhi * 8];
        aql[ch] = *(const f16x8*)&ql[qrow + ch * 32 + lhi * 8];
    }

    // staging: 512 threads, thread covers row sr (0..63), 16B slot su
    const int sr = w * 8 + (lane >> 3);
    const int su = lane & 7;
    const size_t kbase = (size_t)bh * 2048 * 64;
    const size_t vbase = (size_t)bh * 64 * 2048;
    const int sd = sr * 64 + ((su ^ (sr & 7)) * 8);

    int4 stk0, stk1, stv;
    auto LOADK = [&](int kt) {
        const size_t g = kbase + (size_t)(kt * 64 + sr) * 64 + su * 8;
        stk0 = *(const int4*)&kh[g];
        stk1 = *(const int4*)&kl[g];
    };
    auto LOADV = [&](int kt) {
        stv = *(const int4*)&vT[vbase + (size_t)sr * 2048 + kt * 64 + su * 8];
    };
    auto WRITEK = [&](int bf) {
        *(int4*)&kst[bf][0][sd] = stk0;
        *(int4*)&kst[bf][1][sd] = stk1;
    };
    auto WRITEV = [&](int bf) {
        *(int4*)&vst[bf][sd] = stv;
    };
    // QK^T for one staged tile -> acc (scaled + masked, unconditional mask)
    auto QKTILE = [&](int cur, int kt, f32x4* acc) {
        #pragma unroll
        for (int nt = 0; nt < 4; ++nt) {
            const int kr = nt * 16 + l15;
            #pragma unroll
            for (int ch = 0; ch < 2; ++ch) {
                const int slot = ch * 4 + lhi;
                const int ad = kr * 64 + ((slot ^ (kr & 7)) * 8);
                f16x8 bh8 = *(const f16x8*)&kst[cur][0][ad];
                f16x8 bl8 = *(const f16x8*)&kst[cur][1][ad];
                acc[nt] = MFMA16(aqh[ch], bh8, acc[nt]);
                acc[nt] = MFMA16(aqh[ch], bl8, acc[nt]);
                acc[nt] = MFMA16(aql[ch], bh8, acc[nt]);
            }
        }
        #pragma unroll
        for (int nt = 0; nt < 4; ++nt) {
            const int key = kt * 64 + nt * 16 + l15;
            #pragma unroll
            for (int r = 0; r < 4; ++r) {
                float s = acc[nt][r] * 0.125f;
                const int row = rw + lhi * 4 + r;
                if (key > row) s = -1e30f;
                acc[nt][r] = s;
            }
        }
    };

    float m[4], l[4];
    #pragma unroll
    for (int r = 0; r < 4; ++r) { m[r] = -1e30f; l[r] = 0.f; }

    // ---- Phase A: stats only ----
    LOADK(0); WRITEK(0); __syncthreads();
    int cur = 0;
    for (int kt = 0; kt < ktmax; ++kt) {
        if (kt + 1 < ktmax) LOADK(kt + 1);
        f32x4 acc[4] = {};
        QKTILE(cur, kt, acc);
        float tmax[4] = {-1e30f, -1e30f, -1e30f, -1e30f};
        #pragma unroll
        for (int nt = 0; nt < 4; ++nt)
            #pragma unroll
            for (int r = 0; r < 4; ++r)
                tmax[r] = fmaxf(tmax[r], acc[nt][r]);
        #pragma unroll
        for (int off = 1; off < 16; off <<= 1)
            #pragma unroll
            for (int r = 0; r < 4; ++r)
                tmax[r] = fmaxf(tmax[r], __shfl_xor(tmax[r], off));
        float esum[4] = {0.f, 0.f, 0.f, 0.f};
        #pragma unroll
        for (int nt = 0; nt < 4; ++nt)
            #pragma unroll
            for (int r = 0; r < 4; ++r)
                esum[r] += __expf(acc[nt][r] - tmax[r]);
        #pragma unroll
        for (int off = 1; off < 16; off <<= 1)
            #pragma unroll
            for (int r = 0; r < 4; ++r)
                esum[r] += __shfl_xor(esum[r], off);
        #pragma unroll
        for (int r = 0; r < 4; ++r) {
            const float mn = fmaxf(m[r], tmax[r]);
            l[r] = l[r] * __expf(m[r] - mn) + esum[r] * __expf(tmax[r] - mn);
            m[r] = mn;
        }
        if (kt + 1 < ktmax) WRITEK(cur ^ 1);
        __syncthreads();
        cur ^= 1;
    }

    float inv[4];
    #pragma unroll
    for (int r = 0; r < 4; ++r) inv[r] = 1.f / l[r];

    // ---- Phase B: recompute + emit ----
    const int r_    = tid >> 4;            // 0..31
    const int c0    = (tid & 15) * 4;      // streaming col (floats)
    const int chunk = c0 >> 3;
    const int cin   = c0 & 7;
    const int arow  = w * 16 + l15;        // A-frag row (0..127)
    const size_t prow_base = ((size_t)bh * 2048 + q0) * 2048;

    f32x4 acc2[4] = {};
    LOADK(0); LOADV(0); WRITEK(0); WRITEV(0); __syncthreads();
    cur = 0;
    for (int kt = 0; kt < 32; ++kt) {
        if (kt < ktmax) {
            if (kt + 1 < ktmax) { LOADK(kt + 1); LOADV(kt + 1); }
            f32x4 acc[4] = {};
            QKTILE(cur, kt, acc);
            // p = exp(s - m) * inv -> swizzled fp16 pa
            #pragma unroll
            for (int nt = 0; nt < 4; ++nt) {
                const int col = nt * 16 + l15;
                const int cc = col >> 3, ci = col & 7;
                #pragma unroll
                for (int r = 0; r < 4; ++r) {
                    const int row = w * 16 + lhi * 4 + r;
                    const float p = __expf(acc[nt][r] - m[r]) * inv[r];
                    pa[row * 64 + ((cc ^ (row & 7)) * 8) + ci] = (half_t)p;
                }
            }
            __syncthreads();   // pa + staging ready
            // PV MFMA: A-frags from pa, B-frags from vst (LDS)
            #pragma unroll
            for (int ch = 0; ch < 2; ++ch) {
                const int slot = ch * 4 + lhi;
                f16x8 af = *(const f16x8*)&pa[arow * 64 + ((slot ^ (arow & 7)) * 8)];
                #pragma unroll
                for (int nt = 0; nt < 4; ++nt) {
                    const int er = nt * 16 + l15;
                    f16x8 bf8 = *(const f16x8*)&vst[cur][er * 64 + ((slot ^ (er & 7)) * 8)];
                    acc2[nt] = MFMA16(af, bf8, acc2[nt]);
                }
            }
            // coalesced fp32 pattern write from pa (nontemporal)
            #pragma unroll
            for (int rep = 0; rep < 4; ++rep) {
                const int row = rep * 32 + r_;
                f16x4 pv4 = *(const f16x4*)&pa[row * 64 + ((chunk ^ (row & 7)) * 8) + cin];
                f32x4 p;
                p[0] = (float)pv4[0]; p[1] = (float)pv4[1];
                p[2] = (float)pv4[2]; p[3] = (float)pv4[3];
                __builtin_nontemporal_store(p,
                    (f32x4*)&pattern[prow_base + (size_t)row * 2048 + kt * 64 + c0]);
            }
            if (kt + 1 < ktmax) { WRITEK(cur ^ 1); WRITEV(cur ^ 1); }
            __syncthreads();   // next staging ready; pa reads done
            cur ^= 1;
        } else {
            f32x4 zz = {0.f, 0.f, 0.f, 0.f};
            #pragma unroll
            for (int rep = 0; rep < 4; ++rep) {
                const int row = rep * 32 + r_;
                __builtin_nontemporal_store(zz,
                    (f32x4*)&pattern[prow_base + (size_t)row * 2048 + kt * 64 + c0]);
            }
        }
    }

    #pragma unroll
    for (int nt = 0; nt < 4; ++nt) {
        const int e = nt * 16 + l15;
        #pragma unroll
        for (int r = 0; r < 4; ++r) {
            const int row = rw + lhi * 4 + r;
            z[((size_t)(b * 2048 + row)) * 1024 + h * 64 + e] = (half_t)acc2[nt][r];
        }
    }
}

// ---------------------------------------------------------------------------
// O projection GEMM: M=8192, N=1024, K=1024, 1-pass fp16 MFMA.
// ---------------------------------------------------------------------------
__global__ __launch_bounds__(256) void k_oproj(
    const half_t* __restrict__ z, const half_t* __restrict__ woT,
    const float* __restrict__ bo, float* __restrict__ out)
{
    __shared__ half_t lds[2][2][128 * 32];
    const int tid = threadIdx.x, w = tid >> 6, lane = tid & 63;
    const int l15 = lane & 15, lhi = lane >> 4;
    const int wm = w >> 1, wn = w & 1;
    const int m0 = blockIdx.y * 128, n0 = blockIdx.x * 128;

    const int r0 = w * 32 + (lane >> 2);
    const int r1 = r0 + 16;
    const int u  = lane & 3;
    const size_t gA0 = (size_t)(m0 + r0) * 1024 + u * 8;
    const size_t gA1 = (size_t)(m0 + r1) * 1024 + u * 8;
    const size_t gB0 = (size_t)(n0 + r0) * 1024 + u * 8;
    const size_t gB1 = (size_t)(n0 + r1) * 1024 + u * 8;
    const int d0 = r0 * 32 + ((u ^ ((r0 >> 1) & 3)) * 8);
    const int d1 = r1 * 32 + ((u ^ ((r1 >> 1) & 3)) * 8);

    int4 st[4];
    auto LOAD = [&](int kb) {
        st[0] = *(const int4*)&z[gA0 + kb];
        st[1] = *(const int4*)&z[gA1 + kb];
        st[2] = *(const int4*)&woT[gB0 + kb];
        st[3] = *(const int4*)&woT[gB1 + kb];
    };
    auto WRITE = [&](int bf) {
        *(int4*)&lds[bf][0][d0] = st[0];
        *(int4*)&lds[bf][0][d1] = st[1];
        *(int4*)&lds[bf][1][d0] = st[2];
        *(int4*)&lds[bf][1][d1] = st[3];
    };

    f32x4 acc[4][4] = {};
    LOAD(0); WRITE(0); __syncthreads();
    int cur = 0;
    for (int ks = 0; ks < 32; ++ks) {
        if (ks < 31) LOAD((ks + 1) * 32);
        f16x8 fa[4], fb[4];
        #pragma unroll
        for (int i = 0; i < 4; ++i) {
            const int ra = wm * 64 + i * 16 + l15;
            fa[i] = *(const f16x8*)&lds[cur][0][ra * 32 + ((lhi ^ ((ra >> 1) & 3)) * 8)];
            const int rb = wn * 64 + i * 16 + l15;
            fb[i] = *(const f16x8*)&lds[cur][1][rb * 32 + ((lhi ^ ((rb >> 1) & 3)) * 8)];
        }
        #pragma unroll
        for (int mi = 0; mi < 4; ++mi)
            #pragma unroll
            for (int ni = 0; ni < 4; ++ni)
                acc[mi][ni] = MFMA16(fa[mi], fb[ni], acc[mi][ni]);
        if (ks < 31) WRITE(cur ^ 1);
        __syncthreads();
        cur ^= 1;
    }

    #pragma unroll
    for (int ni = 0; ni < 4; ++ni) {
        const int n = n0 + wn * 64 + ni * 16 + l15;
        const float bb = bo[n];
        #pragma unroll
        for (int mi = 0; mi < 4; ++mi)
            #pragma unroll
            for (int r = 0; r < 4; ++r) {
                const int m = m0 + wm * 64 + mi * 16 + lhi * 4 + r;
                __builtin_nontemporal_store(acc[mi][ni][r] + bb,
                                            &out[(size_t)m * 1024 + n]);
            }
    }
}

// ---------------------------------------------------------------------------
extern "C" void kernel_launch(void* const* d_in, const int* in_sizes, int n_in,
                              void* d_out, int out_size, void* d_ws, size_t ws_size,
                              hipStream_t stream) {
    const float* x  = (const float*)d_in[0];
    const float* Wq = (const float*)d_in[1];
    const float* bq = (const float*)d_in[2];
    const float* Wk = (const float*)d_in[3];
    const float* bk = (const float*)d_in[4];
    const float* Wv = (const float*)d_in[5];
    const float* bv = (const float*)d_in[6];
    const float* Wo = (const float*)d_in[7];
    const float* bo = (const float*)d_in[8];

    float* out      = (float*)d_out;
    float* attn_out = out;
    float* pattern  = out + (size_t)8192 * 1024;

    char* wsb = (char*)d_ws;
    const size_t M16 = 16777216;
    half_t* qh  = (half_t*)(wsb + 0 * M16);
    half_t* ql  = (half_t*)(wsb + 1 * M16);
    half_t* kh  = (half_t*)(wsb + 2 * M16);
    half_t* kl  = (half_t*)(wsb + 3 * M16);
    half_t* vT  = (half_t*)(wsb + 4 * M16);
    half_t* xh  = (half_t*)(wsb + 5 * M16);
    half_t* xl  = (half_t*)(wsb + 6 * M16);
    half_t* wh  = (half_t*)(wsb + 7 * M16);                 // 6 MiB
    half_t* wl  = (half_t*)(wsb + 7 * M16 + 6291456);       // 6 MiB
    half_t* woT = (half_t*)(wsb + 7 * M16 + 12582912);      // 2 MiB
    half_t* zbuf = xh;                                      // alias, dead after k_proj

    k_conv_x <<<4096, 256, 0, stream>>>(x, xh, xl);
    k_conv_w <<<768,  256, 0, stream>>>(Wq, Wk, Wv, wh, wl);
    k_conv_wo<<<256,  256, 0, stream>>>(Wo, woT);
    k_proj   <<<dim3(24, 64), 256, 0, stream>>>(xh, xl, wh, wl, bq, bk, bv,
                                                qh, ql, kh, kl, vT);
    k_attn   <<<dim3(1024), 512, 0, stream>>>(qh, ql, kh, kl, vT,
                                              pattern, zbuf);
    k_oproj  <<<dim3(8, 64),  256, 0, stream>>>(zbuf, woT, bo, attn_out);
}

// Round 11
// 495.635 us; speedup vs baseline: 2.9311x; 1.0792x over previous
//
#include <hip/hip_runtime.h>
#include <hip/hip_bf16.h>

// B=4, S=2048, D_MODEL=1024, H=16, E=64, M=8192 rows, bh = b*16+h (64)
// Precision: fp32 value = hi + lo (2x fp16, ~24 mantissa bits, fp32-exact).
// Products via 3 MFMA passes (hh, hl, lh); ll ~ 2^-24 rel -> dropped.
// V path and PV/O GEMMs: single-pass fp16 (error << thresholds).
// MFMA shape: mfma_f32_16x16x32_f16.
//   A-frag: lane l holds A[m=l&15][k=(l>>4)*8+j]  (16B contiguous)
//   B-frag: lane l holds B[k=(l>>4)*8+j][n=l&15]  (read from [n][k]-major array)
//   C/D  : lane l holds D[row=(l>>4)*4+r][col=l&15]

typedef _Float16 half_t;
typedef __attribute__((ext_vector_type(8))) _Float16 f16x8;
typedef __attribute__((ext_vector_type(4))) _Float16 f16x4;
typedef __attribute__((ext_vector_type(4))) float f32x4;

#define MFMA16(a, b, c) __builtin_amdgcn_mfma_f32_16x16x32_f16(a, b, c, 0, 0, 0)

__device__ __forceinline__ void split2(float v, half_t& h, half_t& l) {
    h = (half_t)v;
    l = (half_t)(v - (float)h);
}

// async global->LDS, 16B per lane; LDS dest = wave-uniform base + lane*16
__device__ __forceinline__ void gload_lds16(const half_t* g, half_t* s) {
    __builtin_amdgcn_global_load_lds(
        (const __attribute__((address_space(1))) void*)g,
        (__attribute__((address_space(3))) void*)s, 16, 0, 0);
}

// ---------------------------------------------------------------------------
// x [8192][1024] fp32 -> xh, xl fp16 planes
// ---------------------------------------------------------------------------
__global__ __launch_bounds__(256) void k_conv_x(
    const float* __restrict__ x, half_t* __restrict__ xh, half_t* __restrict__ xl)
{
    const size_t i = ((size_t)blockIdx.x * 256 + threadIdx.x) * 8;
    float4 a = *(const float4*)&x[i];
    float4 b = *(const float4*)&x[i + 4];
    float v[8] = {a.x, a.y, a.z, a.w, b.x, b.y, b.z, b.w};
    f16x8 H, L;
    #pragma unroll
    for (int j = 0; j < 8; ++j) {
        half_t hh, hl; split2(v[j], hh, hl);
        H[j] = hh; L[j] = hl;
    }
    *(f16x8*)&xh[i] = H;
    *(f16x8*)&xl[i] = L;
}

// ---------------------------------------------------------------------------
// W_{Q,K,V} [16][1024 d][64 e] fp32 -> wh, wl fp16 [n=3072][k=1024] (transposed)
// ---------------------------------------------------------------------------
__global__ __launch_bounds__(256) void k_conv_w(
    const float* __restrict__ Wq, const float* __restrict__ Wk, const float* __restrict__ Wv,
    half_t* __restrict__ wh, half_t* __restrict__ wl)
{
    const int bid = blockIdx.x;
    const int mat = bid >> 8, h = (bid >> 4) & 15, dt = bid & 15;
    const float* W = (mat == 0) ? Wq : (mat == 1) ? Wk : Wv;
    __shared__ float t[64][65];
    const int tid = threadIdx.x;
    #pragma unroll
    for (int rep = 0; rep < 4; ++rep) {
        int idx = tid + rep * 256;
        int r = idx >> 4, c4 = (idx & 15) * 4;
        float4 v4 = *(const float4*)&W[(size_t)h * 65536 + (size_t)(dt * 64 + r) * 64 + c4];
        t[r][c4 + 0] = v4.x; t[r][c4 + 1] = v4.y;
        t[r][c4 + 2] = v4.z; t[r][c4 + 3] = v4.w;
    }
    __syncthreads();
    #pragma unroll
    for (int rep = 0; rep < 4; ++rep) {
        int idx = tid + rep * 256;
        int e = idx >> 4, g = (idx & 15) * 4;
        size_t o = ((size_t)(mat * 1024 + h * 64 + e)) * 1024 + dt * 64 + g;
        #pragma unroll
        for (int j = 0; j < 4; ++j) {
            half_t hh, hl; split2(t[g + j][e], hh, hl);
            wh[o + j] = hh; wl[o + j] = hl;
        }
    }
}

// W_O [1024 hd][1024 dm] fp32 -> woT fp16 [dm][hd]
__global__ __launch_bounds__(256) void k_conv_wo(
    const float* __restrict__ Wo, half_t* __restrict__ woT)
{
    const int bi = blockIdx.x >> 4, bj = blockIdx.x & 15;
    __shared__ float t[64][65];
    const int tid = threadIdx.x;
    #pragma unroll
    for (int rep = 0; rep < 4; ++rep) {
        int idx = tid + rep * 256;
        int r = idx >> 4, c4 = (idx & 15) * 4;
        float4 v4 = *(const float4*)&Wo[(size_t)(bi * 64 + r) * 1024 + bj * 64 + c4];
        t[r][c4 + 0] = v4.x; t[r][c4 + 1] = v4.y;
        t[r][c4 + 2] = v4.z; t[r][c4 + 3] = v4.w;
    }
    __syncthreads();
    #pragma unroll
    for (int rep = 0; rep < 4; ++rep) {
        int idx = tid + rep * 256;
        int dm = idx >> 4, g = (idx & 15) * 4;
        size_t o = (size_t)(bj * 64 + dm) * 1024 + bi * 64 + g;
        #pragma unroll
        for (int j = 0; j < 4; ++j)
            woT[o + j] = (half_t)t[g + j][dm];
    }
}

// ---------------------------------------------------------------------------
// QKV projection GEMM: M=8192, N=3072, K=1024.
// Q/K n-blocks: 3-pass fp16-split; V n-blocks (n0>=2048): 1-pass.
// Staging via global_load_lds width=16 (linear LDS dest, pre-swizzled global
// source chunk: src chunk = u ^ ((row>>1)&3); read side XORs the same way).
// ---------------------------------------------------------------------------
__global__ __launch_bounds__(256) void k_proj(
    const half_t* __restrict__ xh, const half_t* __restrict__ xl,
    const half_t* __restrict__ wh, const half_t* __restrict__ wl,
    const float* __restrict__ bq, const float* __restrict__ bk, const float* __restrict__ bv,
    half_t* __restrict__ oqh, half_t* __restrict__ oql,
    half_t* __restrict__ okh, half_t* __restrict__ okl,
    half_t* __restrict__ ovT)
{
    __shared__ half_t lds[2][4][128 * 32];   // [buf][Ah,Al,Bh,Bl][row*32 + c]
    const int tid = threadIdx.x, w = tid >> 6, lane = tid & 63;
    const int l15 = lane & 15, lhi = lane >> 4;
    const int wm = w >> 1, wn = w & 1;
    const int m0 = blockIdx.y * 128, n0 = blockIdx.x * 128;
    const bool isv = (n0 >= 2048);          // V block: single-pass

    const int srow = tid >> 2;              // 0..63 within half
    const int schk = tid & 3;

    auto STAGE = [&](int bf, int kb) {
        #pragma unroll
        for (int p = 0; p < 4; ++p) {
            if (isv && (p & 1)) continue;
            const half_t* gp = (p == 0) ? xh : (p == 1) ? xl : (p == 2) ? wh : wl;
            const int row0g = (p < 2) ? m0 : n0;
            #pragma unroll
            for (int hh = 0; hh < 2; ++hh) {
                const int row = hh * 64 + srow;
                const int swc = schk ^ ((row >> 1) & 3);
                const half_t* src = gp + (size_t)(row0g + row) * 1024 + kb + swc * 8;
                half_t* dst = &lds[bf][p][hh * 2048 + w * 512];   // +lane*8 implicit
                gload_lds16(src, dst);
            }
        }
    };

    f32x4 acc[4][4] = {};

    STAGE(0, 0);
    __syncthreads();
    int cur = 0;
    for (int ks = 0; ks < 32; ++ks) {
        if (ks < 31) STAGE(cur ^ 1, (ks + 1) * 32);
        f16x8 fah[4], fal[4], fbh[4], fbl[4];
        #pragma unroll
        for (int i = 0; i < 4; ++i) {
            const int ra = wm * 64 + i * 16 + l15;
            const int aa = ra * 32 + ((lhi ^ ((ra >> 1) & 3)) * 8);
            fah[i] = *(const f16x8*)&lds[cur][0][aa];
            const int rb = wn * 64 + i * 16 + l15;
            const int ab = rb * 32 + ((lhi ^ ((rb >> 1) & 3)) * 8);
            fbh[i] = *(const f16x8*)&lds[cur][2][ab];
            if (!isv) {
                fal[i] = *(const f16x8*)&lds[cur][1][aa];
                fbl[i] = *(const f16x8*)&lds[cur][3][ab];
            }
        }
        if (isv) {
            #pragma unroll
            for (int mi = 0; mi < 4; ++mi)
                #pragma unroll
                for (int ni = 0; ni < 4; ++ni)
                    acc[mi][ni] = MFMA16(fah[mi], fbh[ni], acc[mi][ni]);
        } else {
            #pragma unroll
            for (int mi = 0; mi < 4; ++mi)
                #pragma unroll
                for (int ni = 0; ni < 4; ++ni) {
                    acc[mi][ni] = MFMA16(fah[mi], fbh[ni], acc[mi][ni]);
                    acc[mi][ni] = MFMA16(fah[mi], fbl[ni], acc[mi][ni]);
                    acc[mi][ni] = MFMA16(fal[mi], fbh[ni], acc[mi][ni]);
                }
        }
        __syncthreads();   // drains vmcnt (buf^1 landed) + all reads of cur done
        cur ^= 1;
    }

    #pragma unroll
    for (int ni = 0; ni < 4; ++ni) {
        const int n = n0 + wn * 64 + ni * 16 + l15;
        const int mat = n >> 10, nn = n & 1023;
        const int h = nn >> 6, e = nn & 63;
        const float bias = (mat == 0 ? bq : mat == 1 ? bk : bv)[h * 64 + e];
        #pragma unroll
        for (int mi = 0; mi < 4; ++mi)
            #pragma unroll
            for (int r = 0; r < 4; ++r) {
                const int m = m0 + wm * 64 + mi * 16 + lhi * 4 + r;
                const int b = m >> 11, s = m & 2047;
                const int bh_i = b * 16 + h;
                const float v = acc[mi][ni][r] + bias;
                if (mat == 2) {
                    ovT[((size_t)bh_i * 64 + e) * 2048 + s] = (half_t)v;
                } else {
                    half_t hh, hl; split2(v, hh, hl);
                    const size_t o = ((size_t)bh_i * 2048 + s) * 64 + e;
                    if (mat == 0) { oqh[o] = hh; oql[o] = hl; }
                    else          { okh[o] = hh; okl[o] = hl; }
                }
            }
    }
}

// ---------------------------------------------------------------------------
// Fused attention, recompute flavor, 128 q-rows/block, 512 threads (8 waves).
// XCD-aware 1D grid; nontemporal pattern stores; K/V staged via
// global_load_lds width=16 (linear LDS dest, pre-swizzled global source).
// Phase A: QK^T 3-pass MFMA per k-tile, online (m,l) in registers only.
// Phase B: recompute QK^T, p = exp(s-m)*inv, bounce fp16 p through swizzled
//          LDS -> coalesced fp32 pattern write + PV A-frags; V from LDS.
// LDS: kst 32KB + vst 16KB + pa 16KB = 64KB -> 2 blocks/CU (16 waves).
// ---------------------------------------------------------------------------
__global__ __launch_bounds__(512, 4) void k_attn(
    const half_t* __restrict__ qh, const half_t* __restrict__ ql,
    const half_t* __restrict__ kh, const half_t* __restrict__ kl,
    const half_t* __restrict__ vT,
    float* __restrict__ pattern, half_t* __restrict__ z)
{
    __shared__ half_t kst[2][2][64 * 64];   // [buf][hi/lo][swizzled] 32 KB
    __shared__ half_t vst[2][64 * 64];      // [buf][e][key swizzled]  16 KB
    __shared__ half_t pa[128 * 64];         // swizzled p tile, 16 KB

    // XCD-aware decode: xcd = bid&7 == bh&7 (assuming round-robin dispatch)
    const int bid = blockIdx.x;
    const int xcd = bid & 7;
    const int idx = bid >> 3;               // 0..127
    const int bh  = xcd + 8 * (idx & 7);    // 0..63
    const int qt  = 15 - (idx >> 3);        // heavy first
    const int b = bh >> 4, h = bh & 15;
    const int tid = threadIdx.x, w = tid >> 6, lane = tid & 63;
    const int l15 = lane & 15, lhi = lane >> 4;
    const int q0 = qt * 128, rw = q0 + w * 16;
    const int ktmax = 2 * qt + 2;

    // Q fragments (persist both phases)
    const size_t qrow = ((size_t)bh * 2048 + rw + l15) * 64;
    f16x8 aqh[2], aql[2];
    #pragma unroll
    for (int ch = 0; ch < 2; ++ch) {
        aqh[ch] = *(const f16x8*)&qh[qrow + ch * 32 + lhi * 8];
        aql[ch] = *(const f16x8*)&ql[qrow + ch * 32 + lhi * 8];
    }

    // staging: thread covers row sr (0..63), 16B slot su; pre-swizzled source
    const int sr = w * 8 + (lane >> 3);
    const int su = lane & 7;
    const int ssw = su ^ (sr & 7);          // source chunk (involution)
    const size_t kbase = (size_t)bh * 2048 * 64;
    const size_t vbase = (size_t)bh * 64 * 2048;

    auto STAGEK = [&](int bf, int kt) {
        const size_t g = kbase + (size_t)(kt * 64 + sr) * 64 + ssw * 8;
        gload_lds16(&kh[g], &kst[bf][0][w * 512]);
        gload_lds16(&kl[g], &kst[bf][1][w * 512]);
    };
    auto STAGEV = [&](int bf, int kt) {
        const size_t g = vbase + (size_t)sr * 2048 + kt * 64 + ssw * 8;
        gload_lds16(&vT[g], &vst[bf][w * 512]);
    };
    // QK^T for one staged tile -> acc (scaled + masked, unconditional mask)
    auto QKTILE = [&](int cur, int kt, f32x4* acc) {
        #pragma unroll
        for (int nt = 0; nt < 4; ++nt) {
            const int kr = nt * 16 + l15;
            #pragma unroll
            for (int ch = 0; ch < 2; ++ch) {
                const int slot = ch * 4 + lhi;
                const int ad = kr * 64 + ((slot ^ (kr & 7)) * 8);
                f16x8 bh8 = *(const f16x8*)&kst[cur][0][ad];
                f16x8 bl8 = *(const f16x8*)&kst[cur][1][ad];
                acc[nt] = MFMA16(aqh[ch], bh8, acc[nt]);
                acc[nt] = MFMA16(aqh[ch], bl8, acc[nt]);
                acc[nt] = MFMA16(aql[ch], bh8, acc[nt]);
            }
        }
        #pragma unroll
        for (int nt = 0; nt < 4; ++nt) {
            const int key = kt * 64 + nt * 16 + l15;
            #pragma unroll
            for (int r = 0; r < 4; ++r) {
                float s = acc[nt][r] * 0.125f;
                const int row = rw + lhi * 4 + r;
                if (key > row) s = -1e30f;
                acc[nt][r] = s;
            }
        }
    };

    float m[4], l[4];
    #pragma unroll
    for (int r = 0; r < 4; ++r) { m[r] = -1e30f; l[r] = 0.f; }

    // ---- Phase A: stats only ----
    STAGEK(0, 0);
    __syncthreads();
    int cur = 0;
    for (int kt = 0; kt < ktmax; ++kt) {
        if (kt + 1 < ktmax) STAGEK(cur ^ 1, kt + 1);
        f32x4 acc[4] = {};
        QKTILE(cur, kt, acc);
        float tmax[4] = {-1e30f, -1e30f, -1e30f, -1e30f};
        #pragma unroll
        for (int nt = 0; nt < 4; ++nt)
            #pragma unroll
            for (int r = 0; r < 4; ++r)
                tmax[r] = fmaxf(tmax[r], acc[nt][r]);
        #pragma unroll
        for (int off = 1; off < 16; off <<= 1)
            #pragma unroll
            for (int r = 0; r < 4; ++r)
                tmax[r] = fmaxf(tmax[r], __shfl_xor(tmax[r], off));
        float esum[4] = {0.f, 0.f, 0.f, 0.f};
        #pragma unroll
        for (int nt = 0; nt < 4; ++nt)
            #pragma unroll
            for (int r = 0; r < 4; ++r)
                esum[r] += __expf(acc[nt][r] - tmax[r]);
        #pragma unroll
        for (int off = 1; off < 16; off <<= 1)
            #pragma unroll
            for (int r = 0; r < 4; ++r)
                esum[r] += __shfl_xor(esum[r], off);
        #pragma unroll
        for (int r = 0; r < 4; ++r) {
            const float mn = fmaxf(m[r], tmax[r]);
            l[r] = l[r] * __expf(m[r] - mn) + esum[r] * __expf(tmax[r] - mn);
            m[r] = mn;
        }
        __syncthreads();
        cur ^= 1;
    }

    float inv[4];
    #pragma unroll
    for (int r = 0; r < 4; ++r) inv[r] = 1.f / l[r];

    // ---- Phase B: recompute + emit ----
    const int r_    = tid >> 4;            // 0..31
    const int c0    = (tid & 15) * 4;      // streaming col (floats)
    const int chunk = c0 >> 3;
    const int cin   = c0 & 7;
    const int arow  = w * 16 + l15;        // A-frag row (0..127)
    const size_t prow_base = ((size_t)bh * 2048 + q0) * 2048;

    f32x4 acc2[4] = {};
    STAGEK(0, 0); STAGEV(0, 0);
    __syncthreads();
    cur = 0;
    for (int kt = 0; kt < 32; ++kt) {
        if (kt < ktmax) {
            if (kt + 1 < ktmax) { STAGEK(cur ^ 1, kt + 1); STAGEV(cur ^ 1, kt + 1); }
            f32x4 acc[4] = {};
            QKTILE(cur, kt, acc);
            // p = exp(s - m) * inv -> swizzled fp16 pa
            #pragma unroll
            for (int nt = 0; nt < 4; ++nt) {
                const int col = nt * 16 + l15;
                const int cc = col >> 3, ci = col & 7;
                #pragma unroll
                for (int r = 0; r < 4; ++r) {
                    const int row = w * 16 + lhi * 4 + r;
                    const float p = __expf(acc[nt][r] - m[r]) * inv[r];
                    pa[row * 64 + ((cc ^ (row & 7)) * 8) + ci] = (half_t)p;
                }
            }
            __syncthreads();   // pa ready (also drains staging)
            // PV MFMA: A-frags from pa, B-frags from vst (LDS)
            #pragma unroll
            for (int ch = 0; ch < 2; ++ch) {
                const int slot = ch * 4 + lhi;
                f16x8 af = *(const f16x8*)&pa[arow * 64 + ((slot ^ (arow & 7)) * 8)];
                #pragma unroll
                for (int nt = 0; nt < 4; ++nt) {
                    const int er = nt * 16 + l15;
                    f16x8 bf8 = *(const f16x8*)&vst[cur][er * 64 + ((slot ^ (er & 7)) * 8)];
                    acc2[nt] = MFMA16(af, bf8, acc2[nt]);
                }
            }
            // coalesced fp32 pattern write from pa (nontemporal)
            #pragma unroll
            for (int rep = 0; rep < 4; ++rep) {
                const int row = rep * 32 + r_;
                f16x4 pv4 = *(const f16x4*)&pa[row * 64 + ((chunk ^ (row & 7)) * 8) + cin];
                f32x4 p;
                p[0] = (float)pv4[0]; p[1] = (float)pv4[1];
                p[2] = (float)pv4[2]; p[3] = (float)pv4[3];
                __builtin_nontemporal_store(p,
                    (f32x4*)&pattern[prow_base + (size_t)row * 2048 + kt * 64 + c0]);
            }
            __syncthreads();   // pa reads done; next staging landed
            cur ^= 1;
        } else {
            f32x4 zz = {0.f, 0.f, 0.f, 0.f};
            #pragma unroll
            for (int rep = 0; rep < 4; ++rep) {
                const int row = rep * 32 + r_;
                __builtin_nontemporal_store(zz,
                    (f32x4*)&pattern[prow_base + (size_t)row * 2048 + kt * 64 + c0]);
            }
        }
    }

    #pragma unroll
    for (int nt = 0; nt < 4; ++nt) {
        const int e = nt * 16 + l15;
        #pragma unroll
        for (int r = 0; r < 4; ++r) {
            const int row = rw + lhi * 4 + r;
            z[((size_t)(b * 2048 + row)) * 1024 + h * 64 + e] = (half_t)acc2[nt][r];
        }
    }
}

// ---------------------------------------------------------------------------
// O projection GEMM: M=8192, N=1024, K=1024, 1-pass fp16 MFMA.
// Staging via global_load_lds width=16 (proj-style, pre-swizzled source).
// ---------------------------------------------------------------------------
__global__ __launch_bounds__(256) void k_oproj(
    const half_t* __restrict__ z, const half_t* __restrict__ woT,
    const float* __restrict__ bo, float* __restrict__ out)
{
    __shared__ half_t lds[2][2][128 * 32];
    const int tid = threadIdx.x, w = tid >> 6, lane = tid & 63;
    const int l15 = lane & 15, lhi = lane >> 4;
    const int wm = w >> 1, wn = w & 1;
    const int m0 = blockIdx.y * 128, n0 = blockIdx.x * 128;

    const int srow = tid >> 2;              // 0..63 within half
    const int schk = tid & 3;

    auto STAGE = [&](int bf, int kb) {
        #pragma unroll
        for (int p = 0; p < 2; ++p) {
            const half_t* gp = p ? woT : z;
            const int row0g = p ? n0 : m0;
            #pragma unroll
            for (int hh = 0; hh < 2; ++hh) {
                const int row = hh * 64 + srow;
                const int swc = schk ^ ((row >> 1) & 3);
                const half_t* src = gp + (size_t)(row0g + row) * 1024 + kb + swc * 8;
                gload_lds16(src, &lds[bf][p][hh * 2048 + w * 512]);
            }
        }
    };

    f32x4 acc[4][4] = {};
    STAGE(0, 0);
    __syncthreads();
    int cur = 0;
    for (int ks = 0; ks < 32; ++ks) {
        if (ks < 31) STAGE(cur ^ 1, (ks + 1) * 32);
        f16x8 fa[4], fb[4];
        #pragma unroll
        for (int i = 0; i < 4; ++i) {
            const int ra = wm * 64 + i * 16 + l15;
            fa[i] = *(const f16x8*)&lds[cur][0][ra * 32 + ((lhi ^ ((ra >> 1) & 3)) * 8)];
            const int rb = wn * 64 + i * 16 + l15;
            fb[i] = *(const f16x8*)&lds[cur][1][rb * 32 + ((lhi ^ ((rb >> 1) & 3)) * 8)];
        }
        #pragma unroll
        for (int mi = 0; mi < 4; ++mi)
            #pragma unroll
            for (int ni = 0; ni < 4; ++ni)
                acc[mi][ni] = MFMA16(fa[mi], fb[ni], acc[mi][ni]);
        __syncthreads();
        cur ^= 1;
    }

    #pragma unroll
    for (int ni = 0; ni < 4; ++ni) {
        const int n = n0 + wn * 64 + ni * 16 + l15;
        const float bb = bo[n];
        #pragma unroll
        for (int mi = 0; mi < 4; ++mi)
            #pragma unroll
            for (int r = 0; r < 4; ++r) {
                const int m = m0 + wm * 64 + mi * 16 + lhi * 4 + r;
                __builtin_nontemporal_store(acc[mi][ni][r] + bb,
                                            &out[(size_t)m * 1024 + n]);
            }
    }
}

// ---------------------------------------------------------------------------
extern "C" void kernel_launch(void* const* d_in, const int* in_sizes, int n_in,
                              void* d_out, int out_size, void* d_ws, size_t ws_size,
                              hipStream_t stream) {
    const float* x  = (const float*)d_in[0];
    const float* Wq = (const float*)d_in[1];
    const float* bq = (const float*)d_in[2];
    const float* Wk = (const float*)d_in[3];
    const float* bk = (const float*)d_in[4];
    const float* Wv = (const float*)d_in[5];
    const float* bv = (const float*)d_in[6];
    const float* Wo = (const float*)d_in[7];
    const float* bo = (const float*)d_in[8];

    float* out      = (float*)d_out;
    float* attn_out = out;
    float* pattern  = out + (size_t)8192 * 1024;

    char* wsb = (char*)d_ws;
    const size_t M16 = 16777216;
    half_t* qh  = (half_t*)(wsb + 0 * M16);
    half_t* ql  = (half_t*)(wsb + 1 * M16);
    half_t* kh  = (half_t*)(wsb + 2 * M16);
    half_t* kl  = (half_t*)(wsb + 3 * M16);
    half_t* vT  = (half_t*)(wsb + 4 * M16);
    half_t* xh  = (half_t*)(wsb + 5 * M16);
    half_t* xl  = (half_t*)(wsb + 6 * M16);
    half_t* wh  = (half_t*)(wsb + 7 * M16);                 // 6 MiB
    half_t* wl  = (half_t*)(wsb + 7 * M16 + 6291456);       // 6 MiB
    half_t* woT = (half_t*)(wsb + 7 * M16 + 12582912);      // 2 MiB
    half_t* zbuf = xh;                                      // alias, dead after k_proj

    k_conv_x <<<4096, 256, 0, stream>>>(x, xh, xl);
    k_conv_w <<<768,  256, 0, stream>>>(Wq, Wk, Wv, wh, wl);
    k_conv_wo<<<256,  256, 0, stream>>>(Wo, woT);
    k_proj   <<<dim3(24, 64), 256, 0, stream>>>(xh, xl, wh, wl, bq, bk, bv,
                                                qh, ql, kh, kl, vT);
    k_attn   <<<dim3(1024), 512, 0, stream>>>(qh, ql, kh, kl, vT,
                                              pattern, zbuf);
    k_oproj  <<<dim3(8, 64),  256, 0, stream>>>(zbuf, woT, bo, attn_out);
}

// Round 12
// 490.417 us; speedup vs baseline: 2.9622x; 1.0106x over previous
//
#include <hip/hip_runtime.h>
#include <hip/hip_bf16.h>

// B=4, S=2048, D_MODEL=1024, H=16, E=64, M=8192 rows, bh = b*16+h (64)
// Precision: fp32 value = hi + lo (2x fp16, ~24 mantissa bits, fp32-exact).
// Products via 3 MFMA passes (hh, hl, lh); ll ~ 2^-24 rel -> dropped.
// V path and PV/O GEMMs: single-pass fp16 (error << thresholds).
// MFMA shape: mfma_f32_16x16x32_f16.
//   A-frag: lane l holds A[m=l&15][k=(l>>4)*8+j]  (16B contiguous)
//   B-frag: lane l holds B[k=(l>>4)*8+j][n=l&15]  (read from [n][k]-major array)
//   C/D  : lane l holds D[row=(l>>4)*4+r][col=l&15]

typedef _Float16 half_t;
typedef __attribute__((ext_vector_type(8))) _Float16 f16x8;
typedef __attribute__((ext_vector_type(4))) _Float16 f16x4;
typedef __attribute__((ext_vector_type(4))) float f32x4;

#define MFMA16(a, b, c) __builtin_amdgcn_mfma_f32_16x16x32_f16(a, b, c, 0, 0, 0)

__device__ __forceinline__ void split2(float v, half_t& h, half_t& l) {
    h = (half_t)v;
    l = (half_t)(v - (float)h);
}

// async global->LDS, 16B per lane; LDS dest = wave-uniform base + lane*16
__device__ __forceinline__ void gload_lds16(const half_t* g, half_t* s) {
    __builtin_amdgcn_global_load_lds(
        (const __attribute__((address_space(1))) void*)g,
        (__attribute__((address_space(3))) void*)s, 16, 0, 0);
}

// ---------------------------------------------------------------------------
// x [8192][1024] fp32 -> xh, xl fp16 planes
// ---------------------------------------------------------------------------
__global__ __launch_bounds__(256) void k_conv_x(
    const float* __restrict__ x, half_t* __restrict__ xh, half_t* __restrict__ xl)
{
    const size_t i = ((size_t)blockIdx.x * 256 + threadIdx.x) * 8;
    float4 a = *(const float4*)&x[i];
    float4 b = *(const float4*)&x[i + 4];
    float v[8] = {a.x, a.y, a.z, a.w, b.x, b.y, b.z, b.w};
    f16x8 H, L;
    #pragma unroll
    for (int j = 0; j < 8; ++j) {
        half_t hh, hl; split2(v[j], hh, hl);
        H[j] = hh; L[j] = hl;
    }
    *(f16x8*)&xh[i] = H;
    *(f16x8*)&xl[i] = L;
}

// ---------------------------------------------------------------------------
// W_{Q,K,V} [16][1024 d][64 e] fp32 -> wh, wl fp16 [n=3072][k=1024] (transposed)
// ---------------------------------------------------------------------------
__global__ __launch_bounds__(256) void k_conv_w(
    const float* __restrict__ Wq, const float* __restrict__ Wk, const float* __restrict__ Wv,
    half_t* __restrict__ wh, half_t* __restrict__ wl)
{
    const int bid = blockIdx.x;
    const int mat = bid >> 8, h = (bid >> 4) & 15, dt = bid & 15;
    const float* W = (mat == 0) ? Wq : (mat == 1) ? Wk : Wv;
    __shared__ float t[64][65];
    const int tid = threadIdx.x;
    #pragma unroll
    for (int rep = 0; rep < 4; ++rep) {
        int idx = tid + rep * 256;
        int r = idx >> 4, c4 = (idx & 15) * 4;
        float4 v4 = *(const float4*)&W[(size_t)h * 65536 + (size_t)(dt * 64 + r) * 64 + c4];
        t[r][c4 + 0] = v4.x; t[r][c4 + 1] = v4.y;
        t[r][c4 + 2] = v4.z; t[r][c4 + 3] = v4.w;
    }
    __syncthreads();
    #pragma unroll
    for (int rep = 0; rep < 4; ++rep) {
        int idx = tid + rep * 256;
        int e = idx >> 4, g = (idx & 15) * 4;
        size_t o = ((size_t)(mat * 1024 + h * 64 + e)) * 1024 + dt * 64 + g;
        #pragma unroll
        for (int j = 0; j < 4; ++j) {
            half_t hh, hl; split2(t[g + j][e], hh, hl);
            wh[o + j] = hh; wl[o + j] = hl;
        }
    }
}

// W_O [1024 hd][1024 dm] fp32 -> woT fp16 [dm][hd]
__global__ __launch_bounds__(256) void k_conv_wo(
    const float* __restrict__ Wo, half_t* __restrict__ woT)
{
    const int bi = blockIdx.x >> 4, bj = blockIdx.x & 15;
    __shared__ float t[64][65];
    const int tid = threadIdx.x;
    #pragma unroll
    for (int rep = 0; rep < 4; ++rep) {
        int idx = tid + rep * 256;
        int r = idx >> 4, c4 = (idx & 15) * 4;
        float4 v4 = *(const float4*)&Wo[(size_t)(bi * 64 + r) * 1024 + bj * 64 + c4];
        t[r][c4 + 0] = v4.x; t[r][c4 + 1] = v4.y;
        t[r][c4 + 2] = v4.z; t[r][c4 + 3] = v4.w;
    }
    __syncthreads();
    #pragma unroll
    for (int rep = 0; rep < 4; ++rep) {
        int idx = tid + rep * 256;
        int dm = idx >> 4, g = (idx & 15) * 4;
        size_t o = (size_t)(bj * 64 + dm) * 1024 + bi * 64 + g;
        #pragma unroll
        for (int j = 0; j < 4; ++j)
            woT[o + j] = (half_t)t[g + j][dm];
    }
}

// ---------------------------------------------------------------------------
// QKV projection GEMM: M=8192, N=3072, K=1024.
// Q/K n-blocks: 3-pass fp16-split; V n-blocks (n0>=2048): 1-pass.
// Staging via global_load_lds width=16 (linear LDS dest, pre-swizzled global
// source chunk: src chunk = u ^ ((row>>1)&3); read side XORs the same way).
// ---------------------------------------------------------------------------
__global__ __launch_bounds__(256) void k_proj(
    const half_t* __restrict__ xh, const half_t* __restrict__ xl,
    const half_t* __restrict__ wh, const half_t* __restrict__ wl,
    const float* __restrict__ bq, const float* __restrict__ bk, const float* __restrict__ bv,
    half_t* __restrict__ oqh, half_t* __restrict__ oql,
    half_t* __restrict__ okh, half_t* __restrict__ okl,
    half_t* __restrict__ ovT)
{
    __shared__ half_t lds[2][4][128 * 32];   // [buf][Ah,Al,Bh,Bl][row*32 + c]
    const int tid = threadIdx.x, w = tid >> 6, lane = tid & 63;
    const int l15 = lane & 15, lhi = lane >> 4;
    const int wm = w >> 1, wn = w & 1;
    const int m0 = blockIdx.y * 128, n0 = blockIdx.x * 128;
    const bool isv = (n0 >= 2048);          // V block: single-pass

    const int srow = tid >> 2;              // 0..63 within half
    const int schk = tid & 3;

    auto STAGE = [&](int bf, int kb) {
        #pragma unroll
        for (int p = 0; p < 4; ++p) {
            if (isv && (p & 1)) continue;
            const half_t* gp = (p == 0) ? xh : (p == 1) ? xl : (p == 2) ? wh : wl;
            const int row0g = (p < 2) ? m0 : n0;
            #pragma unroll
            for (int hh = 0; hh < 2; ++hh) {
                const int row = hh * 64 + srow;
                const int swc = schk ^ ((row >> 1) & 3);
                const half_t* src = gp + (size_t)(row0g + row) * 1024 + kb + swc * 8;
                half_t* dst = &lds[bf][p][hh * 2048 + w * 512];   // +lane*8 implicit
                gload_lds16(src, dst);
            }
        }
    };

    f32x4 acc[4][4] = {};

    STAGE(0, 0);
    __syncthreads();
    int cur = 0;
    for (int ks = 0; ks < 32; ++ks) {
        if (ks < 31) STAGE(cur ^ 1, (ks + 1) * 32);
        f16x8 fah[4], fal[4], fbh[4], fbl[4];
        #pragma unroll
        for (int i = 0; i < 4; ++i) {
            const int ra = wm * 64 + i * 16 + l15;
            const int aa = ra * 32 + ((lhi ^ ((ra >> 1) & 3)) * 8);
            fah[i] = *(const f16x8*)&lds[cur][0][aa];
            const int rb = wn * 64 + i * 16 + l15;
            const int ab = rb * 32 + ((lhi ^ ((rb >> 1) & 3)) * 8);
            fbh[i] = *(const f16x8*)&lds[cur][2][ab];
            if (!isv) {
                fal[i] = *(const f16x8*)&lds[cur][1][aa];
                fbl[i] = *(const f16x8*)&lds[cur][3][ab];
            }
        }
        if (isv) {
            #pragma unroll
            for (int mi = 0; mi < 4; ++mi)
                #pragma unroll
                for (int ni = 0; ni < 4; ++ni)
                    acc[mi][ni] = MFMA16(fah[mi], fbh[ni], acc[mi][ni]);
        } else {
            #pragma unroll
            for (int mi = 0; mi < 4; ++mi)
                #pragma unroll
                for (int ni = 0; ni < 4; ++ni) {
                    acc[mi][ni] = MFMA16(fah[mi], fbh[ni], acc[mi][ni]);
                    acc[mi][ni] = MFMA16(fah[mi], fbl[ni], acc[mi][ni]);
                    acc[mi][ni] = MFMA16(fal[mi], fbh[ni], acc[mi][ni]);
                }
        }
        __syncthreads();   // drains vmcnt (buf^1 landed) + all reads of cur done
        cur ^= 1;
    }

    #pragma unroll
    for (int ni = 0; ni < 4; ++ni) {
        const int n = n0 + wn * 64 + ni * 16 + l15;
        const int mat = n >> 10, nn = n & 1023;
        const int h = nn >> 6, e = nn & 63;
        const float bias = (mat == 0 ? bq : mat == 1 ? bk : bv)[h * 64 + e];
        #pragma unroll
        for (int mi = 0; mi < 4; ++mi)
            #pragma unroll
            for (int r = 0; r < 4; ++r) {
                const int m = m0 + wm * 64 + mi * 16 + lhi * 4 + r;
                const int b = m >> 11, s = m & 2047;
                const int bh_i = b * 16 + h;
                const float v = acc[mi][ni][r] + bias;
                if (mat == 2) {
                    ovT[((size_t)bh_i * 64 + e) * 2048 + s] = (half_t)v;
                } else {
                    half_t hh, hl; split2(v, hh, hl);
                    const size_t o = ((size_t)bh_i * 2048 + s) * 64 + e;
                    if (mat == 0) { oqh[o] = hh; oql[o] = hl; }
                    else          { okh[o] = hh; okl[o] = hl; }
                }
            }
    }
}

// ---------------------------------------------------------------------------
// Fused attention, recompute flavor, 128 q-rows/block, 512 threads (8 waves).
// XCD-aware 1D grid; nontemporal pattern stores; K/V staged via
// global_load_lds width=16 (linear LDS dest, pre-swizzled global source).
// Phase A: QK^T 3-pass MFMA per k-tile, online (m,l) in registers only.
// Phase B: recompute QK^T, p = exp(s-m)*inv -> pa[kt&1] (double-buffered);
//          barrier1 -> PV MFMA (pa + vst) -> barrier2 -> nt pattern store
//          (fire-and-forget; drains at NEXT tile's barrier1, hidden under
//          the next QKTILE's 24 MFMAs).
// LDS: kst 32KB + vst 16KB + pa 32KB = 80KB -> 2 blocks/CU (16 waves).
// ---------------------------------------------------------------------------
__global__ __launch_bounds__(512, 4) void k_attn(
    const half_t* __restrict__ qh, const half_t* __restrict__ ql,
    const half_t* __restrict__ kh, const half_t* __restrict__ kl,
    const half_t* __restrict__ vT,
    float* __restrict__ pattern, half_t* __restrict__ z)
{
    __shared__ half_t kst[2][2][64 * 64];   // [buf][hi/lo][swizzled] 32 KB
    __shared__ half_t vst[2][64 * 64];      // [buf][e][key swizzled]  16 KB
    __shared__ half_t pa[2][128 * 64];      // double-buffered p tile, 32 KB

    // XCD-aware decode: xcd = bid&7 == bh&7 (assuming round-robin dispatch)
    const int bid = blockIdx.x;
    const int xcd = bid & 7;
    const int idx = bid >> 3;               // 0..127
    const int bh  = xcd + 8 * (idx & 7);    // 0..63
    const int qt  = 15 - (idx >> 3);        // heavy first
    const int b = bh >> 4, h = bh & 15;
    const int tid = threadIdx.x, w = tid >> 6, lane = tid & 63;
    const int l15 = lane & 15, lhi = lane >> 4;
    const int q0 = qt * 128, rw = q0 + w * 16;
    const int ktmax = 2 * qt + 2;

    // Q fragments (persist both phases)
    const size_t qrow = ((size_t)bh * 2048 + rw + l15) * 64;
    f16x8 aqh[2], aql[2];
    #pragma unroll
    for (int ch = 0; ch < 2; ++ch) {
        aqh[ch] = *(const f16x8*)&qh[qrow + ch * 32 + lhi * 8];
        aql[ch] = *(const f16x8*)&ql[qrow + ch * 32 + lhi * 8];
    }

    // staging: thread covers row sr (0..63), 16B slot su; pre-swizzled source
    const int sr = w * 8 + (lane >> 3);
    const int su = lane & 7;
    const int ssw = su ^ (sr & 7);          // source chunk (involution)
    const size_t kbase = (size_t)bh * 2048 * 64;
    const size_t vbase = (size_t)bh * 64 * 2048;

    auto STAGEK = [&](int bf, int kt) {
        const size_t g = kbase + (size_t)(kt * 64 + sr) * 64 + ssw * 8;
        gload_lds16(&kh[g], &kst[bf][0][w * 512]);
        gload_lds16(&kl[g], &kst[bf][1][w * 512]);
    };
    auto STAGEV = [&](int bf, int kt) {
        const size_t g = vbase + (size_t)sr * 2048 + kt * 64 + ssw * 8;
        gload_lds16(&vT[g], &vst[bf][w * 512]);
    };
    // QK^T for one staged tile -> acc (scaled + masked, unconditional mask)
    auto QKTILE = [&](int cur, int kt, f32x4* acc) {
        #pragma unroll
        for (int nt = 0; nt < 4; ++nt) {
            const int kr = nt * 16 + l15;
            #pragma unroll
            for (int ch = 0; ch < 2; ++ch) {
                const int slot = ch * 4 + lhi;
                const int ad = kr * 64 + ((slot ^ (kr & 7)) * 8);
                f16x8 bh8 = *(const f16x8*)&kst[cur][0][ad];
                f16x8 bl8 = *(const f16x8*)&kst[cur][1][ad];
                acc[nt] = MFMA16(aqh[ch], bh8, acc[nt]);
                acc[nt] = MFMA16(aqh[ch], bl8, acc[nt]);
                acc[nt] = MFMA16(aql[ch], bh8, acc[nt]);
            }
        }
        #pragma unroll
        for (int nt = 0; nt < 4; ++nt) {
            const int key = kt * 64 + nt * 16 + l15;
            #pragma unroll
            for (int r = 0; r < 4; ++r) {
                float s = acc[nt][r] * 0.125f;
                const int row = rw + lhi * 4 + r;
                if (key > row) s = -1e30f;
                acc[nt][r] = s;
            }
        }
    };

    float m[4], l[4];
    #pragma unroll
    for (int r = 0; r < 4; ++r) { m[r] = -1e30f; l[r] = 0.f; }

    // ---- Phase A: stats only ----
    STAGEK(0, 0);
    __syncthreads();
    int cur = 0;
    for (int kt = 0; kt < ktmax; ++kt) {
        if (kt + 1 < ktmax) STAGEK(cur ^ 1, kt + 1);
        f32x4 acc[4] = {};
        QKTILE(cur, kt, acc);
        float tmax[4] = {-1e30f, -1e30f, -1e30f, -1e30f};
        #pragma unroll
        for (int nt = 0; nt < 4; ++nt)
            #pragma unroll
            for (int r = 0; r < 4; ++r)
                tmax[r] = fmaxf(tmax[r], acc[nt][r]);
        #pragma unroll
        for (int off = 1; off < 16; off <<= 1)
            #pragma unroll
            for (int r = 0; r < 4; ++r)
                tmax[r] = fmaxf(tmax[r], __shfl_xor(tmax[r], off));
        float esum[4] = {0.f, 0.f, 0.f, 0.f};
        #pragma unroll
        for (int nt = 0; nt < 4; ++nt)
            #pragma unroll
            for (int r = 0; r < 4; ++r)
                esum[r] += __expf(acc[nt][r] - tmax[r]);
        #pragma unroll
        for (int off = 1; off < 16; off <<= 1)
            #pragma unroll
            for (int r = 0; r < 4; ++r)
                esum[r] += __shfl_xor(esum[r], off);
        #pragma unroll
        for (int r = 0; r < 4; ++r) {
            const float mn = fmaxf(m[r], tmax[r]);
            l[r] = l[r] * __expf(m[r] - mn) + esum[r] * __expf(tmax[r] - mn);
            m[r] = mn;
        }
        __syncthreads();
        cur ^= 1;
    }

    float inv[4];
    #pragma unroll
    for (int r = 0; r < 4; ++r) inv[r] = 1.f / l[r];

    // ---- Phase B: recompute + emit ----
    const int r_    = tid >> 4;            // 0..31
    const int c0    = (tid & 15) * 4;      // streaming col (floats)
    const int chunk = c0 >> 3;
    const int cin   = c0 & 7;
    const int arow  = w * 16 + l15;        // A-frag row (0..127)
    const size_t prow_base = ((size_t)bh * 2048 + q0) * 2048;

    f32x4 acc2[4] = {};
    STAGEK(0, 0); STAGEV(0, 0);
    __syncthreads();
    cur = 0;
    for (int kt = 0; kt < 32; ++kt) {
        if (kt < ktmax) {
            const int pb = kt & 1;
            if (kt + 1 < ktmax) { STAGEK(cur ^ 1, kt + 1); STAGEV(cur ^ 1, kt + 1); }
            f32x4 acc[4] = {};
            QKTILE(cur, kt, acc);
            // p = exp(s - m) * inv -> swizzled fp16 pa[pb]
            #pragma unroll
            for (int nt = 0; nt < 4; ++nt) {
                const int col = nt * 16 + l15;
                const int cc = col >> 3, ci = col & 7;
                #pragma unroll
                for (int r = 0; r < 4; ++r) {
                    const int row = w * 16 + lhi * 4 + r;
                    const float p = __expf(acc[nt][r] - m[r]) * inv[r];
                    pa[pb][row * 64 + ((cc ^ (row & 7)) * 8) + ci] = (half_t)p;
                }
            }
            __syncthreads();   // barrier1: pa[pb] ready; staging landed;
                               // previous tile's nt stores drained here
            // PV MFMA: A-frags from pa[pb], B-frags from vst (LDS)
            #pragma unroll
            for (int ch = 0; ch < 2; ++ch) {
                const int slot = ch * 4 + lhi;
                f16x8 af = *(const f16x8*)&pa[pb][arow * 64 + ((slot ^ (arow & 7)) * 8)];
                #pragma unroll
                for (int nt = 0; nt < 4; ++nt) {
                    const int er = nt * 16 + l15;
                    f16x8 bf8 = *(const f16x8*)&vst[cur][er * 64 + ((slot ^ (er & 7)) * 8)];
                    acc2[nt] = MFMA16(af, bf8, acc2[nt]);
                }
            }
            __syncthreads();   // barrier2: vst/kst reads done -> next STAGE safe
            // nt pattern store from pa[pb] (fire-and-forget; no drain here —
            // next write to pa[pb] is at kt+2, after barrier1(kt+2))
            #pragma unroll
            for (int rep = 0; rep < 4; ++rep) {
                const int row = rep * 32 + r_;
                f16x4 pv4 = *(const f16x4*)&pa[pb][row * 64 + ((chunk ^ (row & 7)) * 8) + cin];
                f32x4 p;
                p[0] = (float)pv4[0]; p[1] = (float)pv4[1];
                p[2] = (float)pv4[2]; p[3] = (float)pv4[3];
                __builtin_nontemporal_store(p,
                    (f32x4*)&pattern[prow_base + (size_t)row * 2048 + kt * 64 + c0]);
            }
            cur ^= 1;
        } else {
            f32x4 zz = {0.f, 0.f, 0.f, 0.f};
            #pragma unroll
            for (int rep = 0; rep < 4; ++rep) {
                const int row = rep * 32 + r_;
                __builtin_nontemporal_store(zz,
                    (f32x4*)&pattern[prow_base + (size_t)row * 2048 + kt * 64 + c0]);
            }
        }
    }

    #pragma unroll
    for (int nt = 0; nt < 4; ++nt) {
        const int e = nt * 16 + l15;
        #pragma unroll
        for (int r = 0; r < 4; ++r) {
            const int row = rw + lhi * 4 + r;
            z[((size_t)(b * 2048 + row)) * 1024 + h * 64 + e] = (half_t)acc2[nt][r];
        }
    }
}

// ---------------------------------------------------------------------------
// O projection GEMM: M=8192, N=1024, K=1024, 1-pass fp16 MFMA.
// Staging via global_load_lds width=16 (proj-style, pre-swizzled source).
// ---------------------------------------------------------------------------
__global__ __launch_bounds__(256) void k_oproj(
    const half_t* __restrict__ z, const half_t* __restrict__ woT,
    const float* __restrict__ bo, float* __restrict__ out)
{
    __shared__ half_t lds[2][2][128 * 32];
    const int tid = threadIdx.x, w = tid >> 6, lane = tid & 63;
    const int l15 = lane & 15, lhi = lane >> 4;
    const int wm = w >> 1, wn = w & 1;
    const int m0 = blockIdx.y * 128, n0 = blockIdx.x * 128;

    const int srow = tid >> 2;              // 0..63 within half
    const int schk = tid & 3;

    auto STAGE = [&](int bf, int kb) {
        #pragma unroll
        for (int p = 0; p < 2; ++p) {
            const half_t* gp = p ? woT : z;
            const int row0g = p ? n0 : m0;
            #pragma unroll
            for (int hh = 0; hh < 2; ++hh) {
                const int row = hh * 64 + srow;
                const int swc = schk ^ ((row >> 1) & 3);
                const half_t* src = gp + (size_t)(row0g + row) * 1024 + kb + swc * 8;
                gload_lds16(src, &lds[bf][p][hh * 2048 + w * 512]);
            }
        }
    };

    f32x4 acc[4][4] = {};
    STAGE(0, 0);
    __syncthreads();
    int cur = 0;
    for (int ks = 0; ks < 32; ++ks) {
        if (ks < 31) STAGE(cur ^ 1, (ks + 1) * 32);
        f16x8 fa[4], fb[4];
        #pragma unroll
        for (int i = 0; i < 4; ++i) {
            const int ra = wm * 64 + i * 16 + l15;
            fa[i] = *(const f16x8*)&lds[cur][0][ra * 32 + ((lhi ^ ((ra >> 1) & 3)) * 8)];
            const int rb = wn * 64 + i * 16 + l15;
            fb[i] = *(const f16x8*)&lds[cur][1][rb * 32 + ((lhi ^ ((rb >> 1) & 3)) * 8)];
        }
        #pragma unroll
        for (int mi = 0; mi < 4; ++mi)
            #pragma unroll
            for (int ni = 0; ni < 4; ++ni)
                acc[mi][ni] = MFMA16(fa[mi], fb[ni], acc[mi][ni]);
        __syncthreads();
        cur ^= 1;
    }

    #pragma unroll
    for (int ni = 0; ni < 4; ++ni) {
        const int n = n0 + wn * 64 + ni * 16 + l15;
        const float bb = bo[n];
        #pragma unroll
        for (int mi = 0; mi < 4; ++mi)
            #pragma unroll
            for (int r = 0; r < 4; ++r) {
                const int m = m0 + wm * 64 + mi * 16 + lhi * 4 + r;
                __builtin_nontemporal_store(acc[mi][ni][r] + bb,
                                            &out[(size_t)m * 1024 + n]);
            }
    }
}

// ---------------------------------------------------------------------------
extern "C" void kernel_launch(void* const* d_in, const int* in_sizes, int n_in,
                              void* d_out, int out_size, void* d_ws, size_t ws_size,
                              hipStream_t stream) {
    const float* x  = (const float*)d_in[0];
    const float* Wq = (const float*)d_in[1];
    const float* bq = (const float*)d_in[2];
    const float* Wk = (const float*)d_in[3];
    const float* bk = (const float*)d_in[4];
    const float* Wv = (const float*)d_in[5];
    const float* bv = (const float*)d_in[6];
    const float* Wo = (const float*)d_in[7];
    const float* bo = (const float*)d_in[8];

    float* out      = (float*)d_out;
    float* attn_out = out;
    float* pattern  = out + (size_t)8192 * 1024;

    char* wsb = (char*)d_ws;
    const size_t M16 = 16777216;
    half_t* qh  = (half_t*)(wsb + 0 * M16);
    half_t* ql  = (half_t*)(wsb + 1 * M16);
    half_t* kh  = (half_t*)(wsb + 2 * M16);
    half_t* kl  = (half_t*)(wsb + 3 * M16);
    half_t* vT  = (half_t*)(wsb + 4 * M16);
    half_t* xh  = (half_t*)(wsb + 5 * M16);
    half_t* xl  = (half_t*)(wsb + 6 * M16);
    half_t* wh  = (half_t*)(wsb + 7 * M16);                 // 6 MiB
    half_t* wl  = (half_t*)(wsb + 7 * M16 + 6291456);       // 6 MiB
    half_t* woT = (half_t*)(wsb + 7 * M16 + 12582912);      // 2 MiB
    half_t* zbuf = xh;                                      // alias, dead after k_proj

    k_conv_x <<<4096, 256, 0, stream>>>(x, xh, xl);
    k_conv_w <<<768,  256, 0, stream>>>(Wq, Wk, Wv, wh, wl);
    k_conv_wo<<<256,  256, 0, stream>>>(Wo, woT);
    k_proj   <<<dim3(24, 64), 256, 0, stream>>>(xh, xl, wh, wl, bq, bk, bv,
                                                qh, ql, kh, kl, vT);
    k_attn   <<<dim3(1024), 512, 0, stream>>>(qh, ql, kh, kl, vT,
                                              pattern, zbuf);
    k_oproj  <<<dim3(8, 64),  256, 0, stream>>>(zbuf, woT, bo, attn_out);
}